// Round 1
// baseline (16994.598 us; speedup 1.0000x reference)
//
#include <hip/hip_runtime.h>
#include <math.h>

// GPT-style forward: L=4, D=1024, H=16, HS=64, F=4096, V=50257, S=2048, B=1.
// Round 0: correct fp32 baseline. Modular kernels: embed, layernorm,
// templated tiled GEMM (BT/GELU/RES/BIAS), wave-per-row flash attention.

#define SEQ 2048
#define DIM 1024
#define NHEAD 16
#define HSZ 64
#define FFN 4096
#define VOCAB 50257
#define NLAYER 4
#define LNEPS 1e-5f

// ---------------- embedding ----------------
__global__ void embed_kernel(const int* __restrict__ ids,
                             const float* __restrict__ tok,
                             const float* __restrict__ pos,
                             float* __restrict__ h) {
  int i = blockIdx.x * blockDim.x + threadIdx.x;
  if (i < SEQ * DIM) {
    int s = i / DIM, d = i % DIM;
    h[i] = tok[(long)ids[s] * DIM + d] + pos[i];
  }
}

// ---------------- layernorm (one block per row, D=1024, 256 threads) ----------------
__global__ void ln_kernel(const float* __restrict__ x, const float* __restrict__ w,
                          const float* __restrict__ b, float* __restrict__ y) {
  int row = blockIdx.x;
  const float* xr = x + (long)row * DIM;
  float* yr = y + (long)row * DIM;
  int tid = threadIdx.x;
  float v0 = xr[tid], v1 = xr[tid + 256], v2 = xr[tid + 512], v3 = xr[tid + 768];
  __shared__ float red[8];
  float s = v0 + v1 + v2 + v3;
#pragma unroll
  for (int o = 32; o >= 1; o >>= 1) s += __shfl_xor(s, o);
  if ((tid & 63) == 0) red[tid >> 6] = s;
  __syncthreads();
  float mean = (red[0] + red[1] + red[2] + red[3]) * (1.f / DIM);
  float d0 = v0 - mean, d1 = v1 - mean, d2 = v2 - mean, d3 = v3 - mean;
  float q = d0 * d0 + d1 * d1 + d2 * d2 + d3 * d3;
#pragma unroll
  for (int o = 32; o >= 1; o >>= 1) q += __shfl_xor(q, o);
  if ((tid & 63) == 0) red[4 + (tid >> 6)] = q;
  __syncthreads();
  float var = (red[4] + red[5] + red[6] + red[7]) * (1.f / DIM);
  float rstd = rsqrtf(var + LNEPS);
  yr[tid] = d0 * rstd * w[tid] + b[tid];
  yr[tid + 256] = d1 * rstd * w[tid + 256] + b[tid + 256];
  yr[tid + 512] = d2 * rstd * w[tid + 512] + b[tid + 512];
  yr[tid + 768] = d3 * rstd * w[tid + 768] + b[tid + 768];
}

// ---------------- tiled fp32 GEMM ----------------
// C[M,N] = (RES ? res : 0) + epilogue(A[M,K] @ B + bias)
// BT=false: B is [K,N] row-major (weights stored [in,out]).
// BT=true:  B is [N,K] row-major (lm_head stored [out,in]).
// M multiple of 64; K multiple of 16; N guarded (vocab not a multiple of 64).
template <bool BT, bool DOGELU, bool RES, bool BIAS>
__global__ void gemm_kernel(const float* __restrict__ A, const float* __restrict__ B,
                            const float* __restrict__ bias, const float* __restrict__ res,
                            float* __restrict__ C, int M, int N, int K) {
  __shared__ float As[16][68];  // [k][m], row stride 272B = 16B-aligned
  __shared__ float Bs[16][68];  // [k][n]
  int tid = threadIdx.x;
  int m0 = blockIdx.y * 64, n0 = blockIdx.x * 64;
  int tx = tid & 15, ty = tid >> 4;
  float acc[4][4] = {};
  for (int k0 = 0; k0 < K; k0 += 16) {
#pragma unroll
    for (int i = 0; i < 4; i++) {
      int li = tid + i * 256;
      int m = li >> 4, kk = li & 15;
      As[kk][m] = A[(long)(m0 + m) * K + k0 + kk];
    }
#pragma unroll
    for (int i = 0; i < 4; i++) {
      int li = tid + i * 256;
      if (BT) {
        int n = li >> 4, kk = li & 15;
        int gn = n0 + n;
        Bs[kk][n] = (gn < N) ? B[(long)gn * K + k0 + kk] : 0.f;
      } else {
        int kk = li >> 6, n = li & 63;
        int gn = n0 + n;
        Bs[kk][n] = (gn < N) ? B[(long)(k0 + kk) * N + gn] : 0.f;
      }
    }
    __syncthreads();
#pragma unroll
    for (int kk = 0; kk < 16; kk++) {
      float a[4], b[4];
#pragma unroll
      for (int i = 0; i < 4; i++) a[i] = As[kk][ty * 4 + i];
#pragma unroll
      for (int j = 0; j < 4; j++) b[j] = Bs[kk][tx * 4 + j];
#pragma unroll
      for (int i = 0; i < 4; i++)
#pragma unroll
        for (int j = 0; j < 4; j++) acc[i][j] += a[i] * b[j];
    }
    __syncthreads();
  }
#pragma unroll
  for (int i = 0; i < 4; i++) {
    int m = m0 + ty * 4 + i;
#pragma unroll
    for (int j = 0; j < 4; j++) {
      int n = n0 + tx * 4 + j;
      if (n < N) {
        float val = acc[i][j];
        if (BIAS) val += bias[n];
        if (DOGELU) val = 0.5f * val * (1.f + erff(val * 0.70710678118f));
        if (RES) val += res[(long)m * N + n];
        C[(long)m * N + n] = val;
      }
    }
  }
}

// ---------------- attention: one wave per (head, q-row), online softmax ----------------
__global__ void attn_kernel(const float* __restrict__ Q, const float* __restrict__ Kb,
                            const float* __restrict__ Vb, float* __restrict__ O) {
  int hh = blockIdx.x;
  int qi = blockIdx.y;
  int t = threadIdx.x;  // 0..63 = head dim
  int col = hh * HSZ + t;
  float qv = Q[(long)qi * DIM + col] * 0.125f;  // 1/sqrt(64) folded into q
  float m = -INFINITY, l = 0.f, acc = 0.f;
  for (int kk = 0; kk <= qi; kk++) {
    float s = qv * Kb[(long)kk * DIM + col];
#pragma unroll
    for (int o = 32; o >= 1; o >>= 1) s += __shfl_xor(s, o);
    float mn = fmaxf(m, s);
    float corr = __expf(m - mn);  // first iter: exp(-inf)=0
    float p = __expf(s - mn);
    l = l * corr + p;
    acc = acc * corr + p * Vb[(long)kk * DIM + col];
    m = mn;
  }
  O[(long)qi * DIM + col] = acc / l;
}

// ---------------- orchestration ----------------
extern "C" void kernel_launch(void* const* d_in, const int* in_sizes, int n_in,
                              void* d_out, int out_size, void* d_ws, size_t ws_size,
                              hipStream_t stream) {
  const int* ids = (const int*)d_in[0];
  const float* tok = (const float*)d_in[1];
  const float* pos = (const float*)d_in[2];
  const float* Wq = (const float*)d_in[3];
  const float* bq = (const float*)d_in[4];
  const float* Wk = (const float*)d_in[5];
  const float* bk = (const float*)d_in[6];
  const float* Wv = (const float*)d_in[7];
  const float* bv = (const float*)d_in[8];
  const float* Wo = (const float*)d_in[9];
  const float* bo = (const float*)d_in[10];
  const float* W1 = (const float*)d_in[11];
  const float* b1 = (const float*)d_in[12];
  const float* W2 = (const float*)d_in[13];
  const float* b2 = (const float*)d_in[14];
  const float* ln1w = (const float*)d_in[15];
  const float* ln1b = (const float*)d_in[16];
  const float* ln2w = (const float*)d_in[17];
  const float* ln2b = (const float*)d_in[18];
  const float* lnfw = (const float*)d_in[19];
  const float* lnfb = (const float*)d_in[20];
  const float* lmh = (const float*)d_in[21];
  float* out = (float*)d_out;

  const long SD = (long)SEQ * DIM;       // 2M floats
  const long SF = (long)SEQ * FFN;       // 8M floats
  float* ws = (float*)d_ws;
  float* h = ws;            // [S,D]
  float* x = h + SD;        // [S,D]
  float* q = x + SD;        // [S,D]
  float* k = q + SD;        // [S,D]
  float* v = k + SD;        // [S,D]
  float* a = v + SD;        // [S,D]
  float* f = a + SD;        // [S,F]
  // total: 6*SD + SF = 20.97M floats = 83.9 MB

  embed_kernel<<<(SEQ * DIM + 255) / 256, 256, 0, stream>>>(ids, tok, pos, h);

  dim3 gD(DIM / 64, SEQ / 64);     // [2048,1024] outputs
  dim3 gF(FFN / 64, SEQ / 64);     // [2048,4096] outputs
  dim3 gV((VOCAB + 63) / 64, SEQ / 64);

  for (int l = 0; l < NLAYER; l++) {
    const float* wq = Wq + (long)l * DIM * DIM;
    const float* wk = Wk + (long)l * DIM * DIM;
    const float* wv = Wv + (long)l * DIM * DIM;
    const float* wo = Wo + (long)l * DIM * DIM;
    const float* w1 = W1 + (long)l * DIM * FFN;
    const float* w2 = W2 + (long)l * FFN * DIM;
    const float* bql = bq + (long)l * DIM;
    const float* bkl = bk + (long)l * DIM;
    const float* bvl = bv + (long)l * DIM;
    const float* bol = bo + (long)l * DIM;
    const float* b1l = b1 + (long)l * FFN;
    const float* b2l = b2 + (long)l * DIM;

    ln_kernel<<<SEQ, 256, 0, stream>>>(h, ln1w + (long)l * DIM, ln1b + (long)l * DIM, x);
    gemm_kernel<false, false, false, true><<<gD, 256, 0, stream>>>(x, wq, bql, nullptr, q, SEQ, DIM, DIM);
    gemm_kernel<false, false, false, true><<<gD, 256, 0, stream>>>(x, wk, bkl, nullptr, k, SEQ, DIM, DIM);
    gemm_kernel<false, false, false, true><<<gD, 256, 0, stream>>>(x, wv, bvl, nullptr, v, SEQ, DIM, DIM);
    attn_kernel<<<dim3(NHEAD, SEQ), 64, 0, stream>>>(q, k, v, a);
    gemm_kernel<false, false, true, true><<<gD, 256, 0, stream>>>(a, wo, bol, h, h, SEQ, DIM, DIM);
    ln_kernel<<<SEQ, 256, 0, stream>>>(h, ln2w + (long)l * DIM, ln2b + (long)l * DIM, x);
    gemm_kernel<false, true, false, true><<<gF, 256, 0, stream>>>(x, w1, b1l, nullptr, f, SEQ, FFN, DIM);
    gemm_kernel<false, false, true, true><<<gD, 256, 0, stream>>>(f, w2, b2l, h, h, SEQ, DIM, FFN);
  }

  ln_kernel<<<SEQ, 256, 0, stream>>>(h, lnfw, lnfb, x);
  gemm_kernel<true, false, false, false><<<gV, 256, 0, stream>>>(x, lmh, nullptr, nullptr, out, SEQ, VOCAB, DIM);
}

// Round 2
// 1557.757 us; speedup vs baseline: 10.9097x; 10.9097x over previous
//
#include <hip/hip_runtime.h>
#include <math.h>
#include <stdint.h>

// GPT fwd, L=4 D=1024 H=16 HS=64 F=4096 V=50257 S=2048.
// Round 1: bf16 MFMA GEMMs (m97 structure: 128x128 tile, BK=32,
// global_load_lds w=16) + 4-wave MFMA flash attention. fp32 residual stream.

#define SEQ 2048
#define DIM 1024
#define NHEAD 16
#define FFN 4096
#define VOCAB 50257
#define NLAYER 4
#define LNEPS 1e-5f
#define QKVD 3072

using bf16x8 = __attribute__((ext_vector_type(8))) short;
using s16x4  = __attribute__((ext_vector_type(4))) short;
using f32x4  = __attribute__((ext_vector_type(4))) float;
using fl4    = __attribute__((ext_vector_type(4))) float;

static __device__ __forceinline__ short f2bf(float f) {
  uint32_t u = __float_as_uint(f);
  u = (u + 0x7fffu + ((u >> 16) & 1u)) >> 16;
  return (short)u;
}
static __device__ __forceinline__ float bf2f(short s) {
  return __uint_as_float(((uint32_t)(uint16_t)s) << 16);
}
static __device__ __forceinline__ void gload_lds16(const void* g, void* l) {
  __builtin_amdgcn_global_load_lds((const __attribute__((address_space(1))) void*)g,
                                   (__attribute__((address_space(3))) void*)l, 16, 0, 0);
}

// ---------------- embedding (fp32 h) ----------------
__global__ void embed_kernel(const int* __restrict__ ids,
                             const float* __restrict__ tok,
                             const float* __restrict__ pos,
                             float* __restrict__ h) {
  int i = blockIdx.x * blockDim.x + threadIdx.x;
  if (i < SEQ * DIM) {
    int s = i / DIM, d = i % DIM;
    h[i] = tok[(long)ids[s] * DIM + d] + pos[i];
  }
}

// ---------------- layernorm: fp32 in -> bf16 out ----------------
__global__ void ln_kernel(const float* __restrict__ x, const float* __restrict__ w,
                          const float* __restrict__ b, short* __restrict__ y) {
  int row = blockIdx.x;
  const float* xr = x + (long)row * DIM;
  short* yr = y + (long)row * DIM;
  int tid = threadIdx.x;
  float v0 = xr[tid], v1 = xr[tid + 256], v2 = xr[tid + 512], v3 = xr[tid + 768];
  __shared__ float red[8];
  float s = v0 + v1 + v2 + v3;
#pragma unroll
  for (int o = 32; o >= 1; o >>= 1) s += __shfl_xor(s, o);
  if ((tid & 63) == 0) red[tid >> 6] = s;
  __syncthreads();
  float mean = (red[0] + red[1] + red[2] + red[3]) * (1.f / DIM);
  float d0 = v0 - mean, d1 = v1 - mean, d2 = v2 - mean, d3 = v3 - mean;
  float q = d0 * d0 + d1 * d1 + d2 * d2 + d3 * d3;
#pragma unroll
  for (int o = 32; o >= 1; o >>= 1) q += __shfl_xor(q, o);
  if ((tid & 63) == 0) red[4 + (tid >> 6)] = q;
  __syncthreads();
  float var = (red[4] + red[5] + red[6] + red[7]) * (1.f / DIM);
  float rstd = rsqrtf(var + LNEPS);
  yr[tid]       = f2bf(d0 * rstd * w[tid] + b[tid]);
  yr[tid + 256] = f2bf(d1 * rstd * w[tid + 256] + b[tid + 256]);
  yr[tid + 512] = f2bf(d2 * rstd * w[tid + 512] + b[tid + 512]);
  yr[tid + 768] = f2bf(d3 * rstd * w[tid + 768] + b[tid + 768]);
}

// ---------------- weight transpose+convert: [K][N] fp32 -> [N][K] bf16 ----------------
__global__ void transpose_w(const float* __restrict__ in, short* __restrict__ out,
                            int K, int N) {
  __shared__ float t[32][33];
  int c0 = blockIdx.x * 32, r0 = blockIdx.y * 32;
  int tx = threadIdx.x & 31, ty = threadIdx.x >> 5;
#pragma unroll
  for (int i = 0; i < 4; i++)
    t[ty + i * 8][tx] = in[(long)(r0 + ty + i * 8) * N + c0 + tx];
  __syncthreads();
#pragma unroll
  for (int i = 0; i < 4; i++)
    out[(long)(c0 + ty + i * 8) * K + r0 + tx] = f2bf(t[tx][ty + i * 8]);
}

// ---------------- fp32 -> bf16 convert (lm_head) ----------------
__global__ void conv_bf16(const float* __restrict__ in, short* __restrict__ out, long n4) {
  long i = (long)blockIdx.x * blockDim.x + threadIdx.x;
  long stride = (long)gridDim.x * blockDim.x;
  for (; i < n4; i += stride) {
    fl4 v = *(const fl4*)(in + i * 4);
    s16x4 o;
    o[0] = f2bf(v[0]); o[1] = f2bf(v[1]); o[2] = f2bf(v[2]); o[3] = f2bf(v[3]);
    *(s16x4*)(out + i * 4) = o;
  }
}

// ---------------- qkv bias concat ----------------
__global__ void bias_cat(const float* __restrict__ bq, const float* __restrict__ bk,
                         const float* __restrict__ bv, float* __restrict__ out) {
  int i = blockIdx.x * 256 + threadIdx.x;
  if (i < QKVD) out[i] = i < DIM ? bq[i] : (i < 2 * DIM ? bk[i - DIM] : bv[i - 2 * DIM]);
}

// ---------------- MFMA GEMM: C[M,N] = epi(A[M,K]bf16 @ Bt[N,K]bf16^T) ----------------
// 128x128 tile, BK=32, 4 waves (each 64x64), global_load_lds staging.
template <bool GELU, bool RES, bool BIAS, bool OUTBF16>
__global__ __launch_bounds__(256) void mfma_gemm(
    const short* __restrict__ A, const short* __restrict__ Bt,
    const float* __restrict__ bias, const float* __restrict__ res,
    void* __restrict__ Cout, int N, int K) {
  __shared__ short As[128 * 32];
  __shared__ short Bs[128 * 32];
  int tid = threadIdx.x;
  int wid = tid >> 6, lane = tid & 63;
  long m0 = (long)blockIdx.y * 128, n0 = (long)blockIdx.x * 128;
  int wr = (wid >> 1) * 64, wc = (wid & 1) * 64;
  int l16 = lane & 15, lk8 = (lane >> 4) * 8;
  f32x4 acc[4][4] = {};
  for (int k0 = 0; k0 < K; k0 += 32) {
#pragma unroll
    for (int i = 0; i < 2; i++) {
      int ca = i * 256 + tid;          // 16B chunk index (0..511)
      int row = ca >> 2, kc = ca & 3;
      int ldsoff = (i * 256 + wid * 64) * 8;  // wave-uniform LDS base (shorts)
      gload_lds16(A + (long)(m0 + row) * K + k0 + kc * 8, (short*)As + ldsoff);
      int rowb = (int)n0 + row;
      if (rowb > N - 1) rowb = N - 1;  // clamp OOB vocab rows
      gload_lds16(Bt + (long)rowb * K + k0 + kc * 8, (short*)Bs + ldsoff);
    }
    __syncthreads();
    bf16x8 af[4], bfr[4];
#pragma unroll
    for (int m = 0; m < 4; m++) af[m] = *(const bf16x8*)&As[(wr + m * 16 + l16) * 32 + lk8];
#pragma unroll
    for (int n = 0; n < 4; n++) bfr[n] = *(const bf16x8*)&Bs[(wc + n * 16 + l16) * 32 + lk8];
#pragma unroll
    for (int m = 0; m < 4; m++)
#pragma unroll
      for (int n = 0; n < 4; n++)
        acc[m][n] = __builtin_amdgcn_mfma_f32_16x16x32_bf16(af[m], bfr[n], acc[m][n], 0, 0, 0);
    __syncthreads();
  }
  int lr4 = (lane >> 4) * 4;
#pragma unroll
  for (int m = 0; m < 4; m++)
#pragma unroll
    for (int n = 0; n < 4; n++)
#pragma unroll
      for (int r = 0; r < 4; r++) {
        long row = m0 + wr + m * 16 + lr4 + r;
        long col = n0 + wc + n * 16 + l16;
        if (col < N) {
          float v = acc[m][n][r];
          if (BIAS) v += bias[col];
          if (GELU) v = 0.5f * v * (1.f + erff(v * 0.70710678118f));
          if (RES) v += res[row * (long)N + col];
          if (OUTBF16) ((short*)Cout)[row * (long)N + col] = f2bf(v);
          else ((float*)Cout)[row * (long)N + col] = v;
        }
      }
}

// ---------------- MFMA flash attention ----------------
// grid (NHEAD, SEQ/64), 256 thr = 4 waves; wave wv owns q rows q0+wv*16..+15.
// K tile [64k][64d] and V^T tile [64d][64k] in LDS, XOR-swizzled (T2-lite).
#define SWZ(row) (((row) & 7) << 4)
__global__ __launch_bounds__(256) void attn_mfma(const short* __restrict__ qkv,
                                                 short* __restrict__ Oa) {
  int hh = blockIdx.x, qb = blockIdx.y;
  int q0 = qb * 64;
  int tid = threadIdx.x, wv = tid >> 6, lane = tid & 63;
  int l16 = lane & 15, lg = lane >> 4;
  int hcol = hh * 64;
  __shared__ short Ks[64 * 64];
  __shared__ short Vt[64 * 64];
  __shared__ short Pl[4][16 * 64];

  // Q fragments (A-operand layout), scale 1/8 folded in (exact in bf16)
  bf16x8 qf[2];
  {
    const short* qrow = qkv + (long)(q0 + wv * 16 + l16) * QKVD + hcol;
#pragma unroll
    for (int dc = 0; dc < 2; dc++) {
      bf16x8 t = *(const bf16x8*)(qrow + dc * 32 + lg * 8);
#pragma unroll
      for (int j = 0; j < 8; j++) t[j] = f2bf(bf2f(t[j]) * 0.125f);
      qf[dc] = t;
    }
  }
  f32x4 of[4] = {};
  float mrun[4], lrun[4];
#pragma unroll
  for (int r = 0; r < 4; r++) { mrun[r] = -3e38f; lrun[r] = 0.f; }

  int nt = q0 / 64 + 1;
  for (int kt = 0; kt < nt; kt++) {
    int k0 = kt * 64;
    __syncthreads();
    // stage K [row=k][d], swizzled, b128
#pragma unroll
    for (int it = 0; it < 2; it++) {
      int row = (tid >> 3) + it * 32, dch = tid & 7;
      bf16x8 kv = *(const bf16x8*)(qkv + (long)(k0 + row) * QKVD + DIM + hcol + dch * 8);
      *(bf16x8*)((char*)Ks + ((row * 128 + dch * 16) ^ SWZ(row))) = kv;
    }
    // stage V^T [row=d][k], swizzled, b64
#pragma unroll
    for (int it = 0; it < 4; it++) {
      int d = tid & 63, kg = (tid >> 6) + it * 4;
      s16x4 vv;
#pragma unroll
      for (int u = 0; u < 4; u++)
        vv[u] = qkv[(long)(k0 + kg * 4 + u) * QKVD + 2 * DIM + hcol + d];
      *(s16x4*)((char*)Vt + ((d * 128 + kg * 8) ^ SWZ(d))) = vv;
    }
    __syncthreads();

    // QK^T: S[16q][64k] as 4 kc-fragments
    f32x4 sacc[4] = {};
#pragma unroll
    for (int kc = 0; kc < 4; kc++)
#pragma unroll
      for (int dc = 0; dc < 2; dc++) {
        int row = kc * 16 + l16;
        bf16x8 kf = *(const bf16x8*)((const char*)Ks + ((row * 128 + dc * 64 + lg * 16) ^ SWZ(row)));
        sacc[kc] = __builtin_amdgcn_mfma_f32_16x16x32_bf16(qf[dc], kf, sacc[kc], 0, 0, 0);
      }

    float sv[4][4], pf[4][4];
#pragma unroll
    for (int kc = 0; kc < 4; kc++)
#pragma unroll
      for (int r = 0; r < 4; r++) sv[kc][r] = sacc[kc][r];
    if (kt == nt - 1) {  // causal mask on diagonal tile
#pragma unroll
      for (int kc = 0; kc < 4; kc++)
#pragma unroll
        for (int r = 0; r < 4; r++) {
          int kg_ = k0 + kc * 16 + l16;
          int rg = q0 + wv * 16 + lg * 4 + r;
          if (kg_ > rg) sv[kc][r] = -3e38f;
        }
    }
    // online softmax per q-row (row data lives in one 16-lane group)
    float corr[4];
#pragma unroll
    for (int r = 0; r < 4; r++) {
      float mt = fmaxf(fmaxf(sv[0][r], sv[1][r]), fmaxf(sv[2][r], sv[3][r]));
#pragma unroll
      for (int o = 8; o >= 1; o >>= 1) mt = fmaxf(mt, __shfl_xor(mt, o));
      float mn = fmaxf(mrun[r], mt);
      corr[r] = __expf(mrun[r] - mn);
      mrun[r] = mn;
      float ps = 0.f;
#pragma unroll
      for (int kc = 0; kc < 4; kc++) {
        float p = __expf(sv[kc][r] - mn);
        pf[kc][r] = p;
        ps += p;
      }
#pragma unroll
      for (int o = 8; o >= 1; o >>= 1) ps += __shfl_xor(ps, o);
      lrun[r] = lrun[r] * corr[r] + ps;
    }
    // rescale O
#pragma unroll
    for (int c = 0; c < 4; c++)
#pragma unroll
      for (int r = 0; r < 4; r++) of[c][r] *= corr[r];
    // P: D-layout -> A-layout via per-wave LDS bounce (bf16)
#pragma unroll
    for (int kc = 0; kc < 4; kc++)
#pragma unroll
      for (int r = 0; r < 4; r++) {
        int row = lg * 4 + r, col = kc * 16 + l16;
        *(short*)((char*)Pl[wv] + ((row * 128 + col * 2) ^ SWZ(row))) = f2bf(pf[kc][r]);
      }
    bf16x8 pfr[2];
#pragma unroll
    for (int kc2 = 0; kc2 < 2; kc2++) {
      int row = l16;
      pfr[kc2] = *(const bf16x8*)((const char*)Pl[wv] + ((row * 128 + kc2 * 64 + lg * 16) ^ SWZ(row)));
    }
    // PV: O[16q][64d] += P[16][64] @ V[64][64]
#pragma unroll
    for (int c = 0; c < 4; c++)
#pragma unroll
      for (int kc2 = 0; kc2 < 2; kc2++) {
        int vrow = c * 16 + l16;
        bf16x8 vf = *(const bf16x8*)((const char*)Vt + ((vrow * 128 + kc2 * 64 + lg * 16) ^ SWZ(vrow)));
        of[c] = __builtin_amdgcn_mfma_f32_16x16x32_bf16(pfr[kc2], vf, of[c], 0, 0, 0);
      }
  }
  // epilogue: O /= l, store bf16
#pragma unroll
  for (int c = 0; c < 4; c++)
#pragma unroll
    for (int r = 0; r < 4; r++) {
      int rowg = q0 + wv * 16 + lg * 4 + r;
      int colg = hcol + c * 16 + l16;
      Oa[(long)rowg * DIM + colg] = f2bf(of[c][r] / lrun[r]);
    }
}

// ---------------- orchestration ----------------
extern "C" void kernel_launch(void* const* d_in, const int* in_sizes, int n_in,
                              void* d_out, int out_size, void* d_ws, size_t ws_size,
                              hipStream_t stream) {
  const int* ids = (const int*)d_in[0];
  const float* tok = (const float*)d_in[1];
  const float* pos = (const float*)d_in[2];
  const float* Wq = (const float*)d_in[3];
  const float* bq = (const float*)d_in[4];
  const float* Wk = (const float*)d_in[5];
  const float* bk = (const float*)d_in[6];
  const float* Wv = (const float*)d_in[7];
  const float* bv = (const float*)d_in[8];
  const float* Wo = (const float*)d_in[9];
  const float* bo = (const float*)d_in[10];
  const float* W1 = (const float*)d_in[11];
  const float* b1 = (const float*)d_in[12];
  const float* W2 = (const float*)d_in[13];
  const float* b2 = (const float*)d_in[14];
  const float* ln1w = (const float*)d_in[15];
  const float* ln1b = (const float*)d_in[16];
  const float* ln2w = (const float*)d_in[17];
  const float* ln2b = (const float*)d_in[18];
  const float* lnfw = (const float*)d_in[19];
  const float* lnfb = (const float*)d_in[20];
  const float* lmh = (const float*)d_in[21];
  float* out = (float*)d_out;

  // workspace layout (peak ~115.5 MB):
  char* wsb = (char*)d_ws;
  float* h = (float*)wsb;                           // 8 MB fp32 residual
  short* x = (short*)(wsb + 8388608);               // 4 MB bf16 LN out
  char* big = wsb + 8388608 + 4194304;
  short* qkv  = (short*)big;                        // 12 MB   [S][3072]
  short* a    = (short*)(big + 12582912);           // 4 MB    [S][1024]
  short* fbuf = (short*)(big + 16777216);           // 16 MB   [S][4096]
  char* wdyn = big + 33554432;
  short* wqkvT = (short*)wdyn;                      // 6 MB  [3072][1024]
  short* woT   = (short*)(wdyn + 6291456);          // 2 MB  [1024][1024]
  short* w1T   = (short*)(wdyn + 8388608);          // 8 MB  [4096][1024]
  short* w2T   = (short*)(wdyn + 16777216);         // 8 MB  [1024][4096]
  float* bias3 = (float*)(wdyn + 25165824);         // 12 KB
  short* lmhB = (short*)big;                        // 103 MB, reused after layers

  embed_kernel<<<(SEQ * DIM + 255) / 256, 256, 0, stream>>>(ids, tok, pos, h);

  dim3 gQKV(QKVD / 128, SEQ / 128);
  dim3 gD(DIM / 128, SEQ / 128);
  dim3 gF(FFN / 128, SEQ / 128);
  dim3 gV((VOCAB + 127) / 128, SEQ / 128);

  for (int l = 0; l < NLAYER; l++) {
    // per-layer weight prep (wdyn reused each layer; stream-serial)
    transpose_w<<<dim3(32, 32), 256, 0, stream>>>(Wq + (long)l * DIM * DIM, wqkvT, DIM, DIM);
    transpose_w<<<dim3(32, 32), 256, 0, stream>>>(Wk + (long)l * DIM * DIM, wqkvT + (long)DIM * DIM, DIM, DIM);
    transpose_w<<<dim3(32, 32), 256, 0, stream>>>(Wv + (long)l * DIM * DIM, wqkvT + (long)2 * DIM * DIM, DIM, DIM);
    transpose_w<<<dim3(32, 32), 256, 0, stream>>>(Wo + (long)l * DIM * DIM, woT, DIM, DIM);
    transpose_w<<<dim3(128, 32), 256, 0, stream>>>(W1 + (long)l * DIM * FFN, w1T, DIM, FFN);
    transpose_w<<<dim3(32, 128), 256, 0, stream>>>(W2 + (long)l * FFN * DIM, w2T, FFN, DIM);
    bias_cat<<<12, 256, 0, stream>>>(bq + (long)l * DIM, bk + (long)l * DIM, bv + (long)l * DIM, bias3);

    ln_kernel<<<SEQ, 256, 0, stream>>>(h, ln1w + (long)l * DIM, ln1b + (long)l * DIM, x);
    mfma_gemm<false, false, true, true><<<gQKV, 256, 0, stream>>>(x, wqkvT, bias3, nullptr, qkv, QKVD, DIM);
    attn_mfma<<<dim3(NHEAD, SEQ / 64), 256, 0, stream>>>(qkv, a);
    mfma_gemm<false, true, true, false><<<gD, 256, 0, stream>>>(a, woT, bo + (long)l * DIM, h, h, DIM, DIM);
    ln_kernel<<<SEQ, 256, 0, stream>>>(h, ln2w + (long)l * DIM, ln2b + (long)l * DIM, x);
    mfma_gemm<true, false, true, true><<<gF, 256, 0, stream>>>(x, w1T, b1 + (long)l * FFN, nullptr, fbuf, FFN, DIM);
    mfma_gemm<false, true, true, false><<<gD, 256, 0, stream>>>(fbuf, w2T, b2 + (long)l * DIM, h, h, DIM, FFN);
  }

  ln_kernel<<<SEQ, 256, 0, stream>>>(h, lnfw, lnfb, x);
  conv_bf16<<<2048, 256, 0, stream>>>(lmh, lmhB, (long)VOCAB * DIM / 4);
  mfma_gemm<false, false, false, false><<<gV, 256, 0, stream>>>(x, lmhB, nullptr, nullptr, out, VOCAB, DIM);
}

// Round 3
// 1517.413 us; speedup vs baseline: 11.1997x; 1.0266x over previous
//
#include <hip/hip_runtime.h>
#include <math.h>
#include <stdint.h>

// GPT fwd, L=4 D=1024 H=16 HS=64 F=4096 V=50257 S=2048.
// Round 2: lm_head m-fastest grid (L2/L3 weight reuse), coalesced V^T
// staging in attention via materialized vt[h][d][s], batched transposes.

#define SEQ 2048
#define DIM 1024
#define NHEAD 16
#define FFN 4096
#define VOCAB 50257
#define NLAYER 4
#define LNEPS 1e-5f
#define QKVD 3072

using bf16x8 = __attribute__((ext_vector_type(8))) short;
using s16x4  = __attribute__((ext_vector_type(4))) short;
using f32x4  = __attribute__((ext_vector_type(4))) float;
using fl4    = __attribute__((ext_vector_type(4))) float;

static __device__ __forceinline__ short f2bf(float f) {
  uint32_t u = __float_as_uint(f);
  u = (u + 0x7fffu + ((u >> 16) & 1u)) >> 16;
  return (short)u;
}
static __device__ __forceinline__ float bf2f(short s) {
  return __uint_as_float(((uint32_t)(uint16_t)s) << 16);
}
static __device__ __forceinline__ void gload_lds16(const void* g, void* l) {
  __builtin_amdgcn_global_load_lds((const __attribute__((address_space(1))) void*)g,
                                   (__attribute__((address_space(3))) void*)l, 16, 0, 0);
}

// ---------------- embedding (fp32 h) ----------------
__global__ void embed_kernel(const int* __restrict__ ids,
                             const float* __restrict__ tok,
                             const float* __restrict__ pos,
                             float* __restrict__ h) {
  int i = blockIdx.x * blockDim.x + threadIdx.x;
  if (i < SEQ * DIM) {
    int s = i / DIM, d = i % DIM;
    h[i] = tok[(long)ids[s] * DIM + d] + pos[i];
  }
}

// ---------------- layernorm: fp32 in -> bf16 out ----------------
__global__ void ln_kernel(const float* __restrict__ x, const float* __restrict__ w,
                          const float* __restrict__ b, short* __restrict__ y) {
  int row = blockIdx.x;
  const float* xr = x + (long)row * DIM;
  short* yr = y + (long)row * DIM;
  int tid = threadIdx.x;
  float v0 = xr[tid], v1 = xr[tid + 256], v2 = xr[tid + 512], v3 = xr[tid + 768];
  __shared__ float red[8];
  float s = v0 + v1 + v2 + v3;
#pragma unroll
  for (int o = 32; o >= 1; o >>= 1) s += __shfl_xor(s, o);
  if ((tid & 63) == 0) red[tid >> 6] = s;
  __syncthreads();
  float mean = (red[0] + red[1] + red[2] + red[3]) * (1.f / DIM);
  float d0 = v0 - mean, d1 = v1 - mean, d2 = v2 - mean, d3 = v3 - mean;
  float q = d0 * d0 + d1 * d1 + d2 * d2 + d3 * d3;
#pragma unroll
  for (int o = 32; o >= 1; o >>= 1) q += __shfl_xor(q, o);
  if ((tid & 63) == 0) red[4 + (tid >> 6)] = q;
  __syncthreads();
  float var = (red[4] + red[5] + red[6] + red[7]) * (1.f / DIM);
  float rstd = rsqrtf(var + LNEPS);
  yr[tid]       = f2bf(d0 * rstd * w[tid] + b[tid]);
  yr[tid + 256] = f2bf(d1 * rstd * w[tid + 256] + b[tid + 256]);
  yr[tid + 512] = f2bf(d2 * rstd * w[tid + 512] + b[tid + 512]);
  yr[tid + 768] = f2bf(d3 * rstd * w[tid + 768] + b[tid + 768]);
}

// ---------------- weight transpose+convert: [K][N] fp32 -> [N][K] bf16 ----------------
__global__ void transpose_w(const float* __restrict__ in, short* __restrict__ out,
                            int K, int N) {
  __shared__ float t[32][33];
  int c0 = blockIdx.x * 32, r0 = blockIdx.y * 32;
  int tx = threadIdx.x & 31, ty = threadIdx.x >> 5;
#pragma unroll
  for (int i = 0; i < 4; i++)
    t[ty + i * 8][tx] = in[(long)(r0 + ty + i * 8) * N + c0 + tx];
  __syncthreads();
#pragma unroll
  for (int i = 0; i < 4; i++)
    out[(long)(c0 + ty + i * 8) * K + r0 + tx] = f2bf(t[tx][ty + i * 8]);
}

// batched 1024x1024 transposes (Wq,Wk,Wv,Wo) in one launch, z picks matrix
struct TW4 { const float* src[4]; short* dst[4]; };
__global__ void transpose_w4(TW4 p) {
  const float* in = p.src[blockIdx.z];
  short* out = p.dst[blockIdx.z];
  __shared__ float t[32][33];
  int c0 = blockIdx.x * 32, r0 = blockIdx.y * 32;
  int tx = threadIdx.x & 31, ty = threadIdx.x >> 5;
#pragma unroll
  for (int i = 0; i < 4; i++)
    t[ty + i * 8][tx] = in[(long)(r0 + ty + i * 8) * DIM + c0 + tx];
  __syncthreads();
#pragma unroll
  for (int i = 0; i < 4; i++)
    out[(long)(c0 + ty + i * 8) * DIM + r0 + tx] = f2bf(t[tx][ty + i * 8]);
}

// ---------------- V transpose: qkv[s][2D + c] (bf16) -> vt[c][s] ----------------
__global__ void transpose_v(const short* __restrict__ qkv, short* __restrict__ vt) {
  __shared__ short t[32][33];
  int c0 = blockIdx.x * 32, s0 = blockIdx.y * 32;
  int tx = threadIdx.x & 31, ty = threadIdx.x >> 5;
#pragma unroll
  for (int i = 0; i < 4; i++)
    t[ty + i * 8][tx] = qkv[(long)(s0 + ty + i * 8) * QKVD + 2 * DIM + c0 + tx];
  __syncthreads();
#pragma unroll
  for (int i = 0; i < 4; i++)
    vt[(long)(c0 + ty + i * 8) * SEQ + s0 + tx] = t[tx][ty + i * 8];
}

// ---------------- fp32 -> bf16 convert (lm_head) ----------------
__global__ void conv_bf16(const float* __restrict__ in, short* __restrict__ out, long n4) {
  long i = (long)blockIdx.x * blockDim.x + threadIdx.x;
  long stride = (long)gridDim.x * blockDim.x;
  for (; i < n4; i += stride) {
    fl4 v = *(const fl4*)(in + i * 4);
    s16x4 o;
    o[0] = f2bf(v[0]); o[1] = f2bf(v[1]); o[2] = f2bf(v[2]); o[3] = f2bf(v[3]);
    *(s16x4*)(out + i * 4) = o;
  }
}

// ---------------- qkv bias concat ----------------
__global__ void bias_cat(const float* __restrict__ bq, const float* __restrict__ bk,
                         const float* __restrict__ bv, float* __restrict__ out) {
  int i = blockIdx.x * 256 + threadIdx.x;
  if (i < QKVD) out[i] = i < DIM ? bq[i] : (i < 2 * DIM ? bk[i - DIM] : bv[i - 2 * DIM]);
}

// ---------------- MFMA GEMM: C[M,N] = epi(A[M,K]bf16 @ Bt[N,K]bf16^T) ----------------
// 128x128 tile, BK=32, 4 waves (each 64x64), global_load_lds staging.
// SWAPG: blockIdx.x = m-tile (fast axis) so one n-tile's weight panel is
// reused by consecutive blocks (lm_head L2/L3 locality).
template <bool GELU, bool RES, bool BIAS, bool OUTBF16, bool SWAPG>
__global__ __launch_bounds__(256) void mfma_gemm(
    const short* __restrict__ A, const short* __restrict__ Bt,
    const float* __restrict__ bias, const float* __restrict__ res,
    void* __restrict__ Cout, int N, int K) {
  __shared__ short As[128 * 32];
  __shared__ short Bs[128 * 32];
  int tid = threadIdx.x;
  int wid = tid >> 6, lane = tid & 63;
  long m0 = (long)(SWAPG ? blockIdx.x : blockIdx.y) * 128;
  long n0 = (long)(SWAPG ? blockIdx.y : blockIdx.x) * 128;
  int wr = (wid >> 1) * 64, wc = (wid & 1) * 64;
  int l16 = lane & 15, lk8 = (lane >> 4) * 8;
  f32x4 acc[4][4] = {};
  for (int k0 = 0; k0 < K; k0 += 32) {
#pragma unroll
    for (int i = 0; i < 2; i++) {
      int ca = i * 256 + tid;          // 16B chunk index (0..511)
      int row = ca >> 2, kc = ca & 3;
      int ldsoff = (i * 256 + wid * 64) * 8;  // wave-uniform LDS base (shorts)
      gload_lds16(A + (long)(m0 + row) * K + k0 + kc * 8, (short*)As + ldsoff);
      int rowb = (int)n0 + row;
      if (rowb > N - 1) rowb = N - 1;  // clamp OOB vocab rows
      gload_lds16(Bt + (long)rowb * K + k0 + kc * 8, (short*)Bs + ldsoff);
    }
    __syncthreads();
    bf16x8 af[4], bfr[4];
#pragma unroll
    for (int m = 0; m < 4; m++) af[m] = *(const bf16x8*)&As[(wr + m * 16 + l16) * 32 + lk8];
#pragma unroll
    for (int n = 0; n < 4; n++) bfr[n] = *(const bf16x8*)&Bs[(wc + n * 16 + l16) * 32 + lk8];
#pragma unroll
    for (int m = 0; m < 4; m++)
#pragma unroll
      for (int n = 0; n < 4; n++)
        acc[m][n] = __builtin_amdgcn_mfma_f32_16x16x32_bf16(af[m], bfr[n], acc[m][n], 0, 0, 0);
    __syncthreads();
  }
  int lr4 = (lane >> 4) * 4;
#pragma unroll
  for (int m = 0; m < 4; m++)
#pragma unroll
    for (int n = 0; n < 4; n++)
#pragma unroll
      for (int r = 0; r < 4; r++) {
        long row = m0 + wr + m * 16 + lr4 + r;
        long col = n0 + wc + n * 16 + l16;
        if (col < N) {
          float v = acc[m][n][r];
          if (BIAS) v += bias[col];
          if (GELU) v = 0.5f * v * (1.f + erff(v * 0.70710678118f));
          if (RES) v += res[row * (long)N + col];
          if (OUTBF16) ((short*)Cout)[row * (long)N + col] = f2bf(v);
          else ((float*)Cout)[row * (long)N + col] = v;
        }
      }
}

// ---------------- MFMA flash attention ----------------
// grid (NHEAD, SEQ/64), 256 thr = 4 waves; wave wv owns q rows q0+wv*16..+15.
// K tile [64k][64d] and V^T tile [64d][64k] in LDS, XOR-swizzled.
#define SWZ(row) (((row) & 7) << 4)
__global__ __launch_bounds__(256) void attn_mfma(const short* __restrict__ qkv,
                                                 const short* __restrict__ vt,
                                                 short* __restrict__ Oa) {
  int hh = blockIdx.x, qb = blockIdx.y;
  int q0 = qb * 64;
  int tid = threadIdx.x, wv = tid >> 6, lane = tid & 63;
  int l16 = lane & 15, lg = lane >> 4;
  int hcol = hh * 64;
  __shared__ short Ks[64 * 64];
  __shared__ short Vt[64 * 64];
  __shared__ short Pl[4][16 * 64];

  // Q fragments (A-operand layout), scale 1/8 folded in (exact in bf16)
  bf16x8 qf[2];
  {
    const short* qrow = qkv + (long)(q0 + wv * 16 + l16) * QKVD + hcol;
#pragma unroll
    for (int dc = 0; dc < 2; dc++) {
      bf16x8 t = *(const bf16x8*)(qrow + dc * 32 + lg * 8);
#pragma unroll
      for (int j = 0; j < 8; j++) t[j] = f2bf(bf2f(t[j]) * 0.125f);
      qf[dc] = t;
    }
  }
  f32x4 of[4] = {};
  float mrun[4], lrun[4];
#pragma unroll
  for (int r = 0; r < 4; r++) { mrun[r] = -3e38f; lrun[r] = 0.f; }

  int nt = q0 / 64 + 1;
  for (int kt = 0; kt < nt; kt++) {
    int k0 = kt * 64;
    __syncthreads();
    // stage K [row=k][d], swizzled, b128 coalesced
#pragma unroll
    for (int it = 0; it < 2; it++) {
      int row = (tid >> 3) + it * 32, dch = tid & 7;
      bf16x8 kv = *(const bf16x8*)(qkv + (long)(k0 + row) * QKVD + DIM + hcol + dch * 8);
      *(bf16x8*)((char*)Ks + ((row * 128 + dch * 16) ^ SWZ(row))) = kv;
    }
    // stage V^T [row=d][k] from vt[h*64+d][s], b128 coalesced
#pragma unroll
    for (int it = 0; it < 2; it++) {
      int row = (tid >> 3) + it * 32, kch = tid & 7;
      bf16x8 vv = *(const bf16x8*)(vt + (long)(hcol + row) * SEQ + k0 + kch * 8);
      *(bf16x8*)((char*)Vt + ((row * 128 + kch * 16) ^ SWZ(row))) = vv;
    }
    __syncthreads();

    // QK^T: S[16q][64k] as 4 kc-fragments
    f32x4 sacc[4] = {};
#pragma unroll
    for (int kc = 0; kc < 4; kc++)
#pragma unroll
      for (int dc = 0; dc < 2; dc++) {
        int row = kc * 16 + l16;
        bf16x8 kf = *(const bf16x8*)((const char*)Ks + ((row * 128 + dc * 64 + lg * 16) ^ SWZ(row)));
        sacc[kc] = __builtin_amdgcn_mfma_f32_16x16x32_bf16(qf[dc], kf, sacc[kc], 0, 0, 0);
      }

    float sv[4][4], pf[4][4];
#pragma unroll
    for (int kc = 0; kc < 4; kc++)
#pragma unroll
      for (int r = 0; r < 4; r++) sv[kc][r] = sacc[kc][r];
    if (kt == nt - 1) {  // causal mask on diagonal tile
#pragma unroll
      for (int kc = 0; kc < 4; kc++)
#pragma unroll
        for (int r = 0; r < 4; r++) {
          int kg_ = k0 + kc * 16 + l16;
          int rg = q0 + wv * 16 + lg * 4 + r;
          if (kg_ > rg) sv[kc][r] = -3e38f;
        }
    }
    // online softmax per q-row (row data lives in one 16-lane group)
    float corr[4];
#pragma unroll
    for (int r = 0; r < 4; r++) {
      float mt = fmaxf(fmaxf(sv[0][r], sv[1][r]), fmaxf(sv[2][r], sv[3][r]));
#pragma unroll
      for (int o = 8; o >= 1; o >>= 1) mt = fmaxf(mt, __shfl_xor(mt, o));
      float mn = fmaxf(mrun[r], mt);
      corr[r] = __expf(mrun[r] - mn);
      mrun[r] = mn;
      float ps = 0.f;
#pragma unroll
      for (int kc = 0; kc < 4; kc++) {
        float p = __expf(sv[kc][r] - mn);
        pf[kc][r] = p;
        ps += p;
      }
#pragma unroll
      for (int o = 8; o >= 1; o >>= 1) ps += __shfl_xor(ps, o);
      lrun[r] = lrun[r] * corr[r] + ps;
    }
    // rescale O
#pragma unroll
    for (int c = 0; c < 4; c++)
#pragma unroll
      for (int r = 0; r < 4; r++) of[c][r] *= corr[r];
    // P: D-layout -> A-layout via per-wave LDS bounce (bf16)
#pragma unroll
    for (int kc = 0; kc < 4; kc++)
#pragma unroll
      for (int r = 0; r < 4; r++) {
        int row = lg * 4 + r, col = kc * 16 + l16;
        *(short*)((char*)Pl[wv] + ((row * 128 + col * 2) ^ SWZ(row))) = f2bf(pf[kc][r]);
      }
    bf16x8 pfr[2];
#pragma unroll
    for (int kc2 = 0; kc2 < 2; kc2++) {
      int row = l16;
      pfr[kc2] = *(const bf16x8*)((const char*)Pl[wv] + ((row * 128 + kc2 * 64 + lg * 16) ^ SWZ(row)));
    }
    // PV: O[16q][64d] += P[16][64] @ V[64][64]
#pragma unroll
    for (int c = 0; c < 4; c++)
#pragma unroll
      for (int kc2 = 0; kc2 < 2; kc2++) {
        int vrow = c * 16 + l16;
        bf16x8 vf = *(const bf16x8*)((const char*)Vt + ((vrow * 128 + kc2 * 64 + lg * 16) ^ SWZ(vrow)));
        of[c] = __builtin_amdgcn_mfma_f32_16x16x32_bf16(pfr[kc2], vf, of[c], 0, 0, 0);
      }
  }
  // epilogue: O /= l, store bf16
#pragma unroll
  for (int c = 0; c < 4; c++)
#pragma unroll
    for (int r = 0; r < 4; r++) {
      int rowg = q0 + wv * 16 + lg * 4 + r;
      int colg = hcol + c * 16 + l16;
      Oa[(long)rowg * DIM + colg] = f2bf(of[c][r] / lrun[r]);
    }
}

// ---------------- orchestration ----------------
extern "C" void kernel_launch(void* const* d_in, const int* in_sizes, int n_in,
                              void* d_out, int out_size, void* d_ws, size_t ws_size,
                              hipStream_t stream) {
  const int* ids = (const int*)d_in[0];
  const float* tok = (const float*)d_in[1];
  const float* pos = (const float*)d_in[2];
  const float* Wq = (const float*)d_in[3];
  const float* bq = (const float*)d_in[4];
  const float* Wk = (const float*)d_in[5];
  const float* bk = (const float*)d_in[6];
  const float* Wv = (const float*)d_in[7];
  const float* bv = (const float*)d_in[8];
  const float* Wo = (const float*)d_in[9];
  const float* bo = (const float*)d_in[10];
  const float* W1 = (const float*)d_in[11];
  const float* b1 = (const float*)d_in[12];
  const float* W2 = (const float*)d_in[13];
  const float* b2 = (const float*)d_in[14];
  const float* ln1w = (const float*)d_in[15];
  const float* ln1b = (const float*)d_in[16];
  const float* ln2w = (const float*)d_in[17];
  const float* ln2b = (const float*)d_in[18];
  const float* lnfw = (const float*)d_in[19];
  const float* lnfb = (const float*)d_in[20];
  const float* lmh = (const float*)d_in[21];
  float* out = (float*)d_out;

  // workspace layout (peak ~119.5 MB):
  char* wsb = (char*)d_ws;
  float* h = (float*)wsb;                           // 8 MB fp32 residual
  short* x = (short*)(wsb + 8388608);               // 4 MB bf16 LN out
  char* big = wsb + 8388608 + 4194304;
  short* qkv  = (short*)big;                        // 12 MB   [S][3072]
  short* a    = (short*)(big + 12582912);           // 4 MB    [S][1024]
  short* vt   = (short*)(big + 16777216);           // 4 MB    [1024][S]
  short* fbuf = (short*)(big + 20971520);           // 16 MB   [S][4096]
  char* wdyn = big + 37748736;
  short* wqkvT = (short*)wdyn;                      // 6 MB  [3072][1024]
  short* woT   = (short*)(wdyn + 6291456);          // 2 MB  [1024][1024]
  short* w1T   = (short*)(wdyn + 8388608);          // 8 MB  [4096][1024]
  short* w2T   = (short*)(wdyn + 16777216);         // 8 MB  [1024][4096]
  float* bias3 = (float*)(wdyn + 25165824);         // 12 KB
  short* lmhB = (short*)big;                        // 103 MB, reused after layers

  embed_kernel<<<(SEQ * DIM + 255) / 256, 256, 0, stream>>>(ids, tok, pos, h);

  dim3 gQKV(QKVD / 128, SEQ / 128);
  dim3 gD(DIM / 128, SEQ / 128);
  dim3 gF(FFN / 128, SEQ / 128);
  dim3 gV(SEQ / 128, (VOCAB + 127) / 128);  // SWAPG: x=m (fast), y=n

  for (int l = 0; l < NLAYER; l++) {
    TW4 tw;
    tw.src[0] = Wq + (long)l * DIM * DIM; tw.dst[0] = wqkvT;
    tw.src[1] = Wk + (long)l * DIM * DIM; tw.dst[1] = wqkvT + (long)DIM * DIM;
    tw.src[2] = Wv + (long)l * DIM * DIM; tw.dst[2] = wqkvT + (long)2 * DIM * DIM;
    tw.src[3] = Wo + (long)l * DIM * DIM; tw.dst[3] = woT;
    transpose_w4<<<dim3(32, 32, 4), 256, 0, stream>>>(tw);
    transpose_w<<<dim3(128, 32), 256, 0, stream>>>(W1 + (long)l * DIM * FFN, w1T, DIM, FFN);
    transpose_w<<<dim3(32, 128), 256, 0, stream>>>(W2 + (long)l * FFN * DIM, w2T, FFN, DIM);
    bias_cat<<<12, 256, 0, stream>>>(bq + (long)l * DIM, bk + (long)l * DIM, bv + (long)l * DIM, bias3);

    ln_kernel<<<SEQ, 256, 0, stream>>>(h, ln1w + (long)l * DIM, ln1b + (long)l * DIM, x);
    mfma_gemm<false, false, true, true, false><<<gQKV, 256, 0, stream>>>(x, wqkvT, bias3, nullptr, qkv, QKVD, DIM);
    transpose_v<<<dim3(32, 64), 256, 0, stream>>>(qkv, vt);
    attn_mfma<<<dim3(NHEAD, SEQ / 64), 256, 0, stream>>>(qkv, vt, a);
    mfma_gemm<false, true, true, false, false><<<gD, 256, 0, stream>>>(a, woT, bo + (long)l * DIM, h, h, DIM, DIM);
    ln_kernel<<<SEQ, 256, 0, stream>>>(h, ln2w + (long)l * DIM, ln2b + (long)l * DIM, x);
    mfma_gemm<true, false, true, true, false><<<gF, 256, 0, stream>>>(x, w1T, b1 + (long)l * FFN, nullptr, fbuf, FFN, DIM);
    mfma_gemm<false, true, true, false, false><<<gD, 256, 0, stream>>>(fbuf, w2T, b2 + (long)l * DIM, h, h, DIM, FFN);
  }

  ln_kernel<<<SEQ, 256, 0, stream>>>(h, lnfw, lnfb, x);
  conv_bf16<<<2048, 256, 0, stream>>>(lmh, lmhB, (long)VOCAB * DIM / 4);
  mfma_gemm<false, false, false, false, true><<<gV, 256, 0, stream>>>(x, lmhB, nullptr, nullptr, out, VOCAB, DIM);
}

// Round 4
// 1424.600 us; speedup vs baseline: 11.9294x; 1.0652x over previous
//
#include <hip/hip_runtime.h>
#include <math.h>
#include <stdint.h>

// GPT fwd, L=4 D=1024 H=16 HS=64 F=4096 V=50257 S=2048.
// Round 4: BK=64 GEMM + both-sides chunk-XOR LDS swizzle (conflict-free
// ds_read_b128), XCD-bijective swizzle on lm_head, attention KVBLK=128.

#define SEQ 2048
#define DIM 1024
#define NHEAD 16
#define FFN 4096
#define VOCAB 50257
#define NLAYER 4
#define LNEPS 1e-5f
#define QKVD 3072
#define KVB 128

using bf16x8 = __attribute__((ext_vector_type(8))) short;
using s16x4  = __attribute__((ext_vector_type(4))) short;
using f32x4  = __attribute__((ext_vector_type(4))) float;
using fl4    = __attribute__((ext_vector_type(4))) float;

static __device__ __forceinline__ short f2bf(float f) {
  uint32_t u = __float_as_uint(f);
  u = (u + 0x7fffu + ((u >> 16) & 1u)) >> 16;
  return (short)u;
}
static __device__ __forceinline__ float bf2f(short s) {
  return __uint_as_float(((uint32_t)(uint16_t)s) << 16);
}
static __device__ __forceinline__ void gload_lds16(const void* g, void* l) {
  __builtin_amdgcn_global_load_lds((const __attribute__((address_space(1))) void*)g,
                                   (__attribute__((address_space(3))) void*)l, 16, 0, 0);
}

// ---------------- embedding (fp32 h) ----------------
__global__ void embed_kernel(const int* __restrict__ ids,
                             const float* __restrict__ tok,
                             const float* __restrict__ pos,
                             float* __restrict__ h) {
  int i = blockIdx.x * blockDim.x + threadIdx.x;
  if (i < SEQ * DIM) {
    int s = i / DIM, d = i % DIM;
    h[i] = tok[(long)ids[s] * DIM + d] + pos[i];
  }
}

// ---------------- layernorm: fp32 in -> bf16 out ----------------
__global__ void ln_kernel(const float* __restrict__ x, const float* __restrict__ w,
                          const float* __restrict__ b, short* __restrict__ y) {
  int row = blockIdx.x;
  const float* xr = x + (long)row * DIM;
  short* yr = y + (long)row * DIM;
  int tid = threadIdx.x;
  float v0 = xr[tid], v1 = xr[tid + 256], v2 = xr[tid + 512], v3 = xr[tid + 768];
  __shared__ float red[8];
  float s = v0 + v1 + v2 + v3;
#pragma unroll
  for (int o = 32; o >= 1; o >>= 1) s += __shfl_xor(s, o);
  if ((tid & 63) == 0) red[tid >> 6] = s;
  __syncthreads();
  float mean = (red[0] + red[1] + red[2] + red[3]) * (1.f / DIM);
  float d0 = v0 - mean, d1 = v1 - mean, d2 = v2 - mean, d3 = v3 - mean;
  float q = d0 * d0 + d1 * d1 + d2 * d2 + d3 * d3;
#pragma unroll
  for (int o = 32; o >= 1; o >>= 1) q += __shfl_xor(q, o);
  if ((tid & 63) == 0) red[4 + (tid >> 6)] = q;
  __syncthreads();
  float var = (red[4] + red[5] + red[6] + red[7]) * (1.f / DIM);
  float rstd = rsqrtf(var + LNEPS);
  yr[tid]       = f2bf(d0 * rstd * w[tid] + b[tid]);
  yr[tid + 256] = f2bf(d1 * rstd * w[tid + 256] + b[tid + 256]);
  yr[tid + 512] = f2bf(d2 * rstd * w[tid + 512] + b[tid + 512]);
  yr[tid + 768] = f2bf(d3 * rstd * w[tid + 768] + b[tid + 768]);
}

// ---------------- weight transpose+convert: [K][N] fp32 -> [N][K] bf16 ----------------
__global__ void transpose_w(const float* __restrict__ in, short* __restrict__ out,
                            int K, int N) {
  __shared__ float t[32][33];
  int c0 = blockIdx.x * 32, r0 = blockIdx.y * 32;
  int tx = threadIdx.x & 31, ty = threadIdx.x >> 5;
#pragma unroll
  for (int i = 0; i < 4; i++)
    t[ty + i * 8][tx] = in[(long)(r0 + ty + i * 8) * N + c0 + tx];
  __syncthreads();
#pragma unroll
  for (int i = 0; i < 4; i++)
    out[(long)(c0 + ty + i * 8) * K + r0 + tx] = f2bf(t[tx][ty + i * 8]);
}

// batched 1024x1024 transposes (Wq,Wk,Wv,Wo) in one launch, z picks matrix
struct TW4 { const float* src[4]; short* dst[4]; };
__global__ void transpose_w4(TW4 p) {
  const float* in = p.src[blockIdx.z];
  short* out = p.dst[blockIdx.z];
  __shared__ float t[32][33];
  int c0 = blockIdx.x * 32, r0 = blockIdx.y * 32;
  int tx = threadIdx.x & 31, ty = threadIdx.x >> 5;
#pragma unroll
  for (int i = 0; i < 4; i++)
    t[ty + i * 8][tx] = in[(long)(r0 + ty + i * 8) * DIM + c0 + tx];
  __syncthreads();
#pragma unroll
  for (int i = 0; i < 4; i++)
    out[(long)(c0 + ty + i * 8) * DIM + r0 + tx] = f2bf(t[tx][ty + i * 8]);
}

// ---------------- V transpose: qkv[s][2D+c] -> vt[c][s], b128 both sides ----------------
__global__ void transpose_v(const short* __restrict__ qkv, short* __restrict__ vt) {
  __shared__ short t[64][72];
  int s0 = blockIdx.x * 64, c0 = blockIdx.y * 64;
  int tid = threadIdx.x;
#pragma unroll
  for (int i = 0; i < 2; i++) {
    int ca = i * 256 + tid;
    int row = ca >> 3, cp = ca & 7;  // row = s offset, cp = 8-col chunk
    bf16x8 v = *(const bf16x8*)(qkv + (long)(s0 + row) * QKVD + 2 * DIM + c0 + cp * 8);
    *(bf16x8*)&t[row][cp * 8] = v;
  }
  __syncthreads();
#pragma unroll
  for (int i = 0; i < 2; i++) {
    int ca = i * 256 + tid;
    int crow = ca >> 3, sp = ca & 7;  // crow = c offset, sp = 8-s chunk
    s16x4 a, b;
#pragma unroll
    for (int u = 0; u < 4; u++) a[u] = t[sp * 8 + u][crow];
#pragma unroll
    for (int u = 0; u < 4; u++) b[u] = t[sp * 8 + 4 + u][crow];
    bf16x8 o;
#pragma unroll
    for (int u = 0; u < 4; u++) { o[u] = a[u]; o[4 + u] = b[u]; }
    *(bf16x8*)(vt + (long)(c0 + crow) * SEQ + s0 + sp * 8) = o;
  }
}

// ---------------- fp32 -> bf16 convert (lm_head) ----------------
__global__ void conv_bf16(const float* __restrict__ in, short* __restrict__ out, long n4) {
  long i = (long)blockIdx.x * blockDim.x + threadIdx.x;
  long stride = (long)gridDim.x * blockDim.x;
  for (; i < n4; i += stride) {
    fl4 v = *(const fl4*)(in + i * 4);
    s16x4 o;
    o[0] = f2bf(v[0]); o[1] = f2bf(v[1]); o[2] = f2bf(v[2]); o[3] = f2bf(v[3]);
    *(s16x4*)(out + i * 4) = o;
  }
}

// ---------------- qkv bias concat ----------------
__global__ void bias_cat(const float* __restrict__ bq, const float* __restrict__ bk,
                         const float* __restrict__ bv, float* __restrict__ out) {
  int i = blockIdx.x * 256 + threadIdx.x;
  if (i < QKVD) out[i] = i < DIM ? bq[i] : (i < 2 * DIM ? bk[i - DIM] : bv[i - 2 * DIM]);
}

// ---------------- MFMA GEMM: C[M,N] = epi(A[M,K]bf16 @ Bt[N,K]bf16^T) ----------------
// 128x128 tile, BK=64, 4 waves (each 64x64). Both-sides chunk-XOR swizzle:
// LDS tile [128 rows][8 chunks of 16B]; logical chunk c stored at physical
// chunk c^(row&7); gload_lds dest stays linear, global SOURCE is pre-swizzled.
template <bool GELU, bool RES, bool BIAS, bool OUTBF16, bool SWAPG, bool XCDSWZ>
__global__ __launch_bounds__(256) void mfma_gemm(
    const short* __restrict__ A, const short* __restrict__ Bt,
    const float* __restrict__ bias, const float* __restrict__ res,
    void* __restrict__ Cout, int N, int K) {
  __shared__ short As[128 * 64];
  __shared__ short Bs[128 * 64];
  int tid = threadIdx.x;
  int wid = tid >> 6, lane = tid & 63;
  int bx = blockIdx.x, by = blockIdx.y;
  if (XCDSWZ) {  // bijective chunked remap (nwg % 8 == 0 guaranteed by caller)
    int gx = gridDim.x;
    int nwg = gx * gridDim.y;
    int flat = by * gx + bx;
    int nf = (flat & 7) * (nwg >> 3) + (flat >> 3);
    bx = nf % gx; by = nf / gx;
  }
  long m0 = (long)(SWAPG ? bx : by) * 128;
  long n0 = (long)(SWAPG ? by : bx) * 128;
  int wr = (wid >> 1) * 64, wc = (wid & 1) * 64;
  int l16 = lane & 15, lg = (lane >> 4);
  f32x4 acc[4][4] = {};
  for (int k0 = 0; k0 < K; k0 += 64) {
#pragma unroll
    for (int i = 0; i < 4; i++) {
      int ca = i * 256 + tid;              // 16B chunk index (0..1023)
      int row = ca >> 3, cp = ca & 7;      // physical chunk within row
      int c = cp ^ (row & 7);              // logical chunk (inverse swizzle)
      int ldsoff = (i * 256 + wid * 64) * 8;  // wave-uniform base (shorts)
      gload_lds16(A + (long)(m0 + row) * K + k0 + c * 8, (short*)As + ldsoff);
      int rowb = (int)n0 + row;
      if (rowb > N - 1) rowb = N - 1;      // clamp OOB vocab rows
      gload_lds16(Bt + (long)rowb * K + k0 + c * 8, (short*)Bs + ldsoff);
    }
    __syncthreads();
#pragma unroll
    for (int ks = 0; ks < 2; ks++) {
      bf16x8 af[4], bfr[4];
#pragma unroll
      for (int m = 0; m < 4; m++) {
        int row = wr + m * 16 + l16;
        af[m] = *(const bf16x8*)((const char*)As + row * 128 + (((ks * 4 + lg) ^ (row & 7)) * 16));
      }
#pragma unroll
      for (int n = 0; n < 4; n++) {
        int row = wc + n * 16 + l16;
        bfr[n] = *(const bf16x8*)((const char*)Bs + row * 128 + (((ks * 4 + lg) ^ (row & 7)) * 16));
      }
#pragma unroll
      for (int m = 0; m < 4; m++)
#pragma unroll
        for (int n = 0; n < 4; n++)
          acc[m][n] = __builtin_amdgcn_mfma_f32_16x16x32_bf16(af[m], bfr[n], acc[m][n], 0, 0, 0);
    }
    __syncthreads();
  }
  int lr4 = lg * 4;
#pragma unroll
  for (int m = 0; m < 4; m++)
#pragma unroll
    for (int n = 0; n < 4; n++)
#pragma unroll
      for (int r = 0; r < 4; r++) {
        long row = m0 + wr + m * 16 + lr4 + r;
        long col = n0 + wc + n * 16 + l16;
        if (col < N) {
          float v = acc[m][n][r];
          if (BIAS) v += bias[col];
          if (GELU) v = 0.5f * v * (1.f + erff(v * 0.70710678118f));
          if (RES) v += res[row * (long)N + col];
          if (OUTBF16) ((short*)Cout)[row * (long)N + col] = f2bf(v);
          else ((float*)Cout)[row * (long)N + col] = v;
        }
      }
}

// ---------------- MFMA flash attention, KVBLK=128 ----------------
// grid (NHEAD, SEQ/64), 256 thr = 4 waves; wave wv owns q rows q0+wv*16..+15.
// Ks[128k][64d], Vt[64d][128k], Pl[wave][16q][128k]; chunk-XOR swizzled.
__global__ __launch_bounds__(256) void attn_mfma(const short* __restrict__ qkv,
                                                 const short* __restrict__ vtg,
                                                 short* __restrict__ Oa) {
  int hh = blockIdx.x, qb = blockIdx.y;
  int q0 = qb * 64;
  int tid = threadIdx.x, wv = tid >> 6, lane = tid & 63;
  int l16 = lane & 15, lg = lane >> 4;
  int hcol = hh * 64;
  __shared__ short Ks[KVB * 64];
  __shared__ short Vt[64 * KVB];
  __shared__ short Pl[4][16 * KVB];

  bf16x8 qf[2];
  {
    const short* qrow = qkv + (long)(q0 + wv * 16 + l16) * QKVD + hcol;
#pragma unroll
    for (int dc = 0; dc < 2; dc++) {
      bf16x8 t = *(const bf16x8*)(qrow + dc * 32 + lg * 8);
#pragma unroll
      for (int j = 0; j < 8; j++) t[j] = f2bf(bf2f(t[j]) * 0.125f);
      qf[dc] = t;
    }
  }
  f32x4 of[4] = {};
  float mrun[4], lrun[4];
#pragma unroll
  for (int r = 0; r < 4; r++) { mrun[r] = -3e38f; lrun[r] = 0.f; }

  int nt = qb / 2 + 1;
  for (int kt = 0; kt < nt; kt++) {
    int k0 = kt * KVB;
    __syncthreads();
    // stage K [128 rows k][8 chunks d], pre-swizzled source
#pragma unroll
    for (int i = 0; i < 4; i++) {
      int ca = i * 256 + tid;
      int row = ca >> 3, cp = ca & 7, c = cp ^ (row & 7);
      int ldsoff = (i * 256 + wv * 64) * 8;
      gload_lds16(qkv + (long)(k0 + row) * QKVD + DIM + hcol + c * 8, (short*)Ks + ldsoff);
    }
    // stage V^T [64 rows d][16 chunks k], pre-swizzled source
#pragma unroll
    for (int i = 0; i < 4; i++) {
      int ca = i * 256 + tid;
      int row = ca >> 4, cp = ca & 15, c = cp ^ (row & 7);
      int ldsoff = (i * 256 + wv * 64) * 8;
      gload_lds16(vtg + (long)(hcol + row) * SEQ + k0 + c * 8, (short*)Vt + ldsoff);
    }
    __syncthreads();

    // QK^T: S[16q][128k] as 8 kc-fragments
    f32x4 sacc[8] = {};
#pragma unroll
    for (int kc = 0; kc < 8; kc++) {
      int row = kc * 16 + l16;
#pragma unroll
      for (int dc = 0; dc < 2; dc++) {
        bf16x8 kf = *(const bf16x8*)((const char*)Ks + row * 128 + (((dc * 4 + lg) ^ (row & 7)) * 16));
        sacc[kc] = __builtin_amdgcn_mfma_f32_16x16x32_bf16(qf[dc], kf, sacc[kc], 0, 0, 0);
      }
    }

    float sv[8][4], pf[8][4];
#pragma unroll
    for (int kc = 0; kc < 8; kc++)
#pragma unroll
      for (int r = 0; r < 4; r++) sv[kc][r] = sacc[kc][r];
    if (kt == nt - 1) {  // causal mask
#pragma unroll
      for (int kc = 0; kc < 8; kc++)
#pragma unroll
        for (int r = 0; r < 4; r++) {
          int kg = k0 + kc * 16 + l16;
          int rg = q0 + wv * 16 + lg * 4 + r;
          if (kg > rg) sv[kc][r] = -3e38f;
        }
    }
    float corr[4];
#pragma unroll
    for (int r = 0; r < 4; r++) {
      float m01 = fmaxf(sv[0][r], sv[1][r]), m23 = fmaxf(sv[2][r], sv[3][r]);
      float m45 = fmaxf(sv[4][r], sv[5][r]), m67 = fmaxf(sv[6][r], sv[7][r]);
      float mt = fmaxf(fmaxf(m01, m23), fmaxf(m45, m67));
#pragma unroll
      for (int o = 8; o >= 1; o >>= 1) mt = fmaxf(mt, __shfl_xor(mt, o));
      float mn = fmaxf(mrun[r], mt);
      corr[r] = __expf(mrun[r] - mn);
      mrun[r] = mn;
      float ps = 0.f;
#pragma unroll
      for (int kc = 0; kc < 8; kc++) {
        float p = __expf(sv[kc][r] - mn);
        pf[kc][r] = p;
        ps += p;
      }
#pragma unroll
      for (int o = 8; o >= 1; o >>= 1) ps += __shfl_xor(ps, o);
      lrun[r] = lrun[r] * corr[r] + ps;
    }
#pragma unroll
    for (int c = 0; c < 4; c++)
#pragma unroll
      for (int r = 0; r < 4; r++) of[c][r] *= corr[r];
    // P: D-layout -> A-layout via per-wave LDS bounce
#pragma unroll
    for (int kc = 0; kc < 8; kc++)
#pragma unroll
      for (int r = 0; r < 4; r++) {
        int row = lg * 4 + r, col = kc * 16 + l16;
        int chunk = col >> 3;
        *(short*)((char*)Pl[wv] + row * 256 + ((chunk ^ (row & 7)) * 16) + (col & 7) * 2) = f2bf(pf[kc][r]);
      }
    bf16x8 pfr[4];
#pragma unroll
    for (int kc2 = 0; kc2 < 4; kc2++) {
      int cl = kc2 * 4 + lg;
      pfr[kc2] = *(const bf16x8*)((const char*)Pl[wv] + l16 * 256 + ((cl ^ (l16 & 7)) * 16));
    }
    // PV: O[16q][64d] += P[16][128] @ V[128][64]
#pragma unroll
    for (int c = 0; c < 4; c++)
#pragma unroll
      for (int kc2 = 0; kc2 < 4; kc2++) {
        int vrow = c * 16 + l16;
        int cl = kc2 * 4 + lg;
        bf16x8 vf = *(const bf16x8*)((const char*)Vt + vrow * 256 + ((cl ^ (vrow & 7)) * 16));
        of[c] = __builtin_amdgcn_mfma_f32_16x16x32_bf16(pfr[kc2], vf, of[c], 0, 0, 0);
      }
  }
#pragma unroll
  for (int c = 0; c < 4; c++)
#pragma unroll
    for (int r = 0; r < 4; r++) {
      int rowg = q0 + wv * 16 + lg * 4 + r;
      int colg = hcol + c * 16 + l16;
      Oa[(long)rowg * DIM + colg] = f2bf(of[c][r] / lrun[r]);
    }
}

// ---------------- orchestration ----------------
extern "C" void kernel_launch(void* const* d_in, const int* in_sizes, int n_in,
                              void* d_out, int out_size, void* d_ws, size_t ws_size,
                              hipStream_t stream) {
  const int* ids = (const int*)d_in[0];
  const float* tok = (const float*)d_in[1];
  const float* pos = (const float*)d_in[2];
  const float* Wq = (const float*)d_in[3];
  const float* bq = (const float*)d_in[4];
  const float* Wk = (const float*)d_in[5];
  const float* bk = (const float*)d_in[6];
  const float* Wv = (const float*)d_in[7];
  const float* bv = (const float*)d_in[8];
  const float* Wo = (const float*)d_in[9];
  const float* bo = (const float*)d_in[10];
  const float* W1 = (const float*)d_in[11];
  const float* b1 = (const float*)d_in[12];
  const float* W2 = (const float*)d_in[13];
  const float* b2 = (const float*)d_in[14];
  const float* ln1w = (const float*)d_in[15];
  const float* ln1b = (const float*)d_in[16];
  const float* ln2w = (const float*)d_in[17];
  const float* ln2b = (const float*)d_in[18];
  const float* lnfw = (const float*)d_in[19];
  const float* lnfb = (const float*)d_in[20];
  const float* lmh = (const float*)d_in[21];
  float* out = (float*)d_out;

  char* wsb = (char*)d_ws;
  float* h = (float*)wsb;                           // 8 MB fp32 residual
  short* x = (short*)(wsb + 8388608);               // 4 MB bf16 LN out
  char* big = wsb + 8388608 + 4194304;
  short* qkv  = (short*)big;                        // 12 MB   [S][3072]
  short* a    = (short*)(big + 12582912);           // 4 MB    [S][1024]
  short* vt   = (short*)(big + 16777216);           // 4 MB    [1024][S]
  short* fbuf = (short*)(big + 20971520);           // 16 MB   [S][4096]
  char* wdyn = big + 37748736;
  short* wqkvT = (short*)wdyn;                      // 6 MB  [3072][1024]
  short* woT   = (short*)(wdyn + 6291456);          // 2 MB  [1024][1024]
  short* w1T   = (short*)(wdyn + 8388608);          // 8 MB  [4096][1024]
  short* w2T   = (short*)(wdyn + 16777216);         // 8 MB  [1024][4096]
  float* bias3 = (float*)(wdyn + 25165824);         // 12 KB
  short* lmhB = (short*)big;                        // 103 MB, reused after layers

  embed_kernel<<<(SEQ * DIM + 255) / 256, 256, 0, stream>>>(ids, tok, pos, h);

  dim3 gQKV(QKVD / 128, SEQ / 128);
  dim3 gD(DIM / 128, SEQ / 128);
  dim3 gF(FFN / 128, SEQ / 128);
  dim3 gV(SEQ / 128, (VOCAB + 127) / 128);  // SWAPG: x=m (fast), y=n; 6288 blocks

  for (int l = 0; l < NLAYER; l++) {
    TW4 tw;
    tw.src[0] = Wq + (long)l * DIM * DIM; tw.dst[0] = wqkvT;
    tw.src[1] = Wk + (long)l * DIM * DIM; tw.dst[1] = wqkvT + (long)DIM * DIM;
    tw.src[2] = Wv + (long)l * DIM * DIM; tw.dst[2] = wqkvT + (long)2 * DIM * DIM;
    tw.src[3] = Wo + (long)l * DIM * DIM; tw.dst[3] = woT;
    transpose_w4<<<dim3(32, 32, 4), 256, 0, stream>>>(tw);
    transpose_w<<<dim3(128, 32), 256, 0, stream>>>(W1 + (long)l * DIM * FFN, w1T, DIM, FFN);
    transpose_w<<<dim3(32, 128), 256, 0, stream>>>(W2 + (long)l * FFN * DIM, w2T, FFN, DIM);
    bias_cat<<<12, 256, 0, stream>>>(bq + (long)l * DIM, bk + (long)l * DIM, bv + (long)l * DIM, bias3);

    ln_kernel<<<SEQ, 256, 0, stream>>>(h, ln1w + (long)l * DIM, ln1b + (long)l * DIM, x);
    mfma_gemm<false, false, true, true, false, false><<<gQKV, 256, 0, stream>>>(x, wqkvT, bias3, nullptr, qkv, QKVD, DIM);
    transpose_v<<<dim3(SEQ / 64, DIM / 64), 256, 0, stream>>>(qkv, vt);
    attn_mfma<<<dim3(NHEAD, SEQ / 64), 256, 0, stream>>>(qkv, vt, a);
    mfma_gemm<false, true, true, false, false, false><<<gD, 256, 0, stream>>>(a, woT, bo + (long)l * DIM, h, h, DIM, DIM);
    ln_kernel<<<SEQ, 256, 0, stream>>>(h, ln2w + (long)l * DIM, ln2b + (long)l * DIM, x);
    mfma_gemm<true, false, true, true, false, false><<<gF, 256, 0, stream>>>(x, w1T, b1 + (long)l * FFN, nullptr, fbuf, FFN, DIM);
    mfma_gemm<false, true, true, false, false, false><<<gD, 256, 0, stream>>>(fbuf, w2T, b2 + (long)l * DIM, h, h, DIM, FFN);
  }

  ln_kernel<<<SEQ, 256, 0, stream>>>(h, lnfw, lnfb, x);
  conv_bf16<<<2048, 256, 0, stream>>>(lmh, lmhB, (long)VOCAB * DIM / 4);
  mfma_gemm<false, false, false, false, true, true><<<gV, 256, 0, stream>>>(x, lmhB, nullptr, nullptr, out, VOCAB, DIM);
}

// Round 5
// 1144.865 us; speedup vs baseline: 14.8442x; 1.2443x over previous
//
#include <hip/hip_runtime.h>
#include <math.h>
#include <stdint.h>

// GPT fwd, L=4 D=1024 H=16 HS=64 F=4096 V=50257 S=2048.
// Round 5: gemm8 = 8-wave 256x128 tile, BK=64, 3-buffer LDS pipeline,
// counted vmcnt(6) (T3/T4), setprio (T5), chunk-XOR swizzle (T2, proven 0
// conflicts), XCD-bijective block swizzle (T1). Split-K for narrow GEMMs.

#define SEQ 2048
#define DIM 1024
#define NHEAD 16
#define FFN 4096
#define VOCAB 50257
#define NLAYER 4
#define LNEPS 1e-5f
#define QKVD 3072
#define KVB 128

using bf16x8 = __attribute__((ext_vector_type(8))) short;
using s16x4  = __attribute__((ext_vector_type(4))) short;
using f32x4  = __attribute__((ext_vector_type(4))) float;
using fl4    = __attribute__((ext_vector_type(4))) float;

static __device__ __forceinline__ short f2bf(float f) {
  uint32_t u = __float_as_uint(f);
  u = (u + 0x7fffu + ((u >> 16) & 1u)) >> 16;
  return (short)u;
}
static __device__ __forceinline__ float bf2f(short s) {
  return __uint_as_float(((uint32_t)(uint16_t)s) << 16);
}
static __device__ __forceinline__ void gload_lds16(const void* g, void* l) {
  __builtin_amdgcn_global_load_lds((const __attribute__((address_space(1))) void*)g,
                                   (__attribute__((address_space(3))) void*)l, 16, 0, 0);
}

// ---------------- embedding (fp32 h) ----------------
__global__ void embed_kernel(const int* __restrict__ ids,
                             const float* __restrict__ tok,
                             const float* __restrict__ pos,
                             float* __restrict__ h) {
  int i = blockIdx.x * blockDim.x + threadIdx.x;
  if (i < SEQ * DIM) {
    int s = i / DIM, d = i % DIM;
    h[i] = tok[(long)ids[s] * DIM + d] + pos[i];
  }
}

// ---------------- layernorm: fp32 in -> bf16 out ----------------
__global__ void ln_kernel(const float* __restrict__ x, const float* __restrict__ w,
                          const float* __restrict__ b, short* __restrict__ y) {
  int row = blockIdx.x;
  const float* xr = x + (long)row * DIM;
  short* yr = y + (long)row * DIM;
  int tid = threadIdx.x;
  float v0 = xr[tid], v1 = xr[tid + 256], v2 = xr[tid + 512], v3 = xr[tid + 768];
  __shared__ float red[8];
  float s = v0 + v1 + v2 + v3;
#pragma unroll
  for (int o = 32; o >= 1; o >>= 1) s += __shfl_xor(s, o);
  if ((tid & 63) == 0) red[tid >> 6] = s;
  __syncthreads();
  float mean = (red[0] + red[1] + red[2] + red[3]) * (1.f / DIM);
  float d0 = v0 - mean, d1 = v1 - mean, d2 = v2 - mean, d3 = v3 - mean;
  float q = d0 * d0 + d1 * d1 + d2 * d2 + d3 * d3;
#pragma unroll
  for (int o = 32; o >= 1; o >>= 1) q += __shfl_xor(q, o);
  if ((tid & 63) == 0) red[4 + (tid >> 6)] = q;
  __syncthreads();
  float var = (red[4] + red[5] + red[6] + red[7]) * (1.f / DIM);
  float rstd = rsqrtf(var + LNEPS);
  yr[tid]       = f2bf(d0 * rstd * w[tid] + b[tid]);
  yr[tid + 256] = f2bf(d1 * rstd * w[tid + 256] + b[tid + 256]);
  yr[tid + 512] = f2bf(d2 * rstd * w[tid + 512] + b[tid + 512]);
  yr[tid + 768] = f2bf(d3 * rstd * w[tid + 768] + b[tid + 768]);
}

// ---------------- weight transpose+convert: [K][N] fp32 -> [N][K] bf16 ----------------
__global__ void transpose_w(const float* __restrict__ in, short* __restrict__ out,
                            int K, int N) {
  __shared__ float t[32][33];
  int c0 = blockIdx.x * 32, r0 = blockIdx.y * 32;
  int tx = threadIdx.x & 31, ty = threadIdx.x >> 5;
#pragma unroll
  for (int i = 0; i < 4; i++)
    t[ty + i * 8][tx] = in[(long)(r0 + ty + i * 8) * N + c0 + tx];
  __syncthreads();
#pragma unroll
  for (int i = 0; i < 4; i++)
    out[(long)(c0 + ty + i * 8) * K + r0 + tx] = f2bf(t[tx][ty + i * 8]);
}

// batched 1024x1024 transposes (Wq,Wk,Wv,Wo) in one launch, z picks matrix
struct TW4 { const float* src[4]; short* dst[4]; };
__global__ void transpose_w4(TW4 p) {
  const float* in = p.src[blockIdx.z];
  short* out = p.dst[blockIdx.z];
  __shared__ float t[32][33];
  int c0 = blockIdx.x * 32, r0 = blockIdx.y * 32;
  int tx = threadIdx.x & 31, ty = threadIdx.x >> 5;
#pragma unroll
  for (int i = 0; i < 4; i++)
    t[ty + i * 8][tx] = in[(long)(r0 + ty + i * 8) * DIM + c0 + tx];
  __syncthreads();
#pragma unroll
  for (int i = 0; i < 4; i++)
    out[(long)(c0 + ty + i * 8) * DIM + r0 + tx] = f2bf(t[tx][ty + i * 8]);
}

// ---------------- V transpose: qkv[s][2D+c] -> vt[c][s], b128 both sides ----------------
__global__ void transpose_v(const short* __restrict__ qkv, short* __restrict__ vt) {
  __shared__ short t[64][72];
  int s0 = blockIdx.x * 64, c0 = blockIdx.y * 64;
  int tid = threadIdx.x;
#pragma unroll
  for (int i = 0; i < 2; i++) {
    int ca = i * 256 + tid;
    int row = ca >> 3, cp = ca & 7;
    bf16x8 v = *(const bf16x8*)(qkv + (long)(s0 + row) * QKVD + 2 * DIM + c0 + cp * 8);
    *(bf16x8*)&t[row][cp * 8] = v;
  }
  __syncthreads();
#pragma unroll
  for (int i = 0; i < 2; i++) {
    int ca = i * 256 + tid;
    int crow = ca >> 3, sp = ca & 7;
    s16x4 a, b;
#pragma unroll
    for (int u = 0; u < 4; u++) a[u] = t[sp * 8 + u][crow];
#pragma unroll
    for (int u = 0; u < 4; u++) b[u] = t[sp * 8 + 4 + u][crow];
    bf16x8 o;
#pragma unroll
    for (int u = 0; u < 4; u++) { o[u] = a[u]; o[4 + u] = b[u]; }
    *(bf16x8*)(vt + (long)(c0 + crow) * SEQ + s0 + sp * 8) = o;
  }
}

// ---------------- fp32 -> bf16 convert (lm_head) ----------------
__global__ void conv_bf16(const float* __restrict__ in, short* __restrict__ out, long n4) {
  long i = (long)blockIdx.x * blockDim.x + threadIdx.x;
  long stride = (long)gridDim.x * blockDim.x;
  for (; i < n4; i += stride) {
    fl4 v = *(const fl4*)(in + i * 4);
    s16x4 o;
    o[0] = f2bf(v[0]); o[1] = f2bf(v[1]); o[2] = f2bf(v[2]); o[3] = f2bf(v[3]);
    *(s16x4*)(out + i * 4) = o;
  }
}

// ---------------- qkv bias concat ----------------
__global__ void bias_cat(const float* __restrict__ bq, const float* __restrict__ bk,
                         const float* __restrict__ bv, float* __restrict__ out) {
  int i = blockIdx.x * 256 + threadIdx.x;
  if (i < QKVD) out[i] = i < DIM ? bq[i] : (i < 2 * DIM ? bk[i - DIM] : bv[i - 2 * DIM]);
}

// ---------------- gemm8: pipelined MFMA GEMM ----------------
// C[M,N] = epi(A[M,K] @ Bt[N,K]^T). 256x128 tile, BK=64, 8 waves (512 thr),
// each wave owns 64x64. 3 LDS buffers (48KB each), prefetch distance 2,
// counted s_waitcnt vmcnt(6) at tile boundary (T4) — never drains to 0 in
// the main loop. Chunk-XOR swizzle (R4-proven, 0 bank conflicts).
// KS>1: grid.z splits K; raw fp32 partials written to Cout + z*M*N.
template <bool GELU, bool RES, bool BIAS, bool OUTBF16, int KS, bool XCDSWZ>
__global__ __launch_bounds__(512) void gemm8(
    const short* __restrict__ A, const short* __restrict__ Bt,
    const float* __restrict__ bias, const float* __restrict__ res,
    void* __restrict__ Cout, int N, int Kfull) {
  __shared__ short lds[3][(256 + 128) * 64];  // 144 KB
  const int tid = threadIdx.x, wid = tid >> 6, lane = tid & 63;
  const int l16 = lane & 15, lg = lane >> 4;
  int bx = blockIdx.x, by = blockIdx.y;
  if (XCDSWZ) {  // bijective chunked remap; caller guarantees nwg % 8 == 0
    int gx = gridDim.x, nwg = gx * gridDim.y;
    int flat = by * gx + bx;
    int nf = (flat & 7) * (nwg >> 3) + (flat >> 3);
    bx = nf % gx; by = nf / gx;
  }
  const long m0 = (long)bx * 256, n0 = (long)by * 128;
  const int K = Kfull / KS;
  const int kbase = blockIdx.z * K;
  const int NT = K / 64;
  const int wr = (wid >> 1) * 64, wc = (wid & 1) * 64;

#define STAGE8(t, b)                                                            \
  {                                                                             \
    short* As_ = lds[b];                                                        \
    short* Bs_ = lds[b] + 256 * 64;                                             \
    int kk_ = kbase + (t) * 64;                                                 \
    _Pragma("unroll")                                                           \
    for (int i_ = 0; i_ < 4; i_++) {                                            \
      int ca_ = i_ * 512 + tid;                                                 \
      int row_ = ca_ >> 3, cp_ = ca_ & 7, c_ = cp_ ^ (row_ & 7);                \
      gload_lds16(A + (m0 + row_) * (long)Kfull + kk_ + c_ * 8,                 \
                  As_ + (i_ * 512 + wid * 64) * 8);                             \
    }                                                                           \
    _Pragma("unroll")                                                           \
    for (int i_ = 0; i_ < 2; i_++) {                                            \
      int ca_ = i_ * 512 + tid;                                                 \
      int row_ = ca_ >> 3, cp_ = ca_ & 7, c_ = cp_ ^ (row_ & 7);                \
      int rowb_ = (int)n0 + row_;                                               \
      if (rowb_ > N - 1) rowb_ = N - 1;                                         \
      gload_lds16(Bt + (long)rowb_ * Kfull + kk_ + c_ * 8,                      \
                  Bs_ + (i_ * 512 + wid * 64) * 8);                             \
    }                                                                           \
  }

  f32x4 acc[4][4] = {};
  // prologue: stage tiles 0 and 1
  STAGE8(0, 0);
  STAGE8(1, 1);
  asm volatile("s_waitcnt vmcnt(6)" ::: "memory");  // tile 0 resident
  __builtin_amdgcn_s_barrier();
  __builtin_amdgcn_sched_barrier(0);

  for (int t = 0; t < NT; t++) {
    const int b = t % 3;
    if (t + 2 < NT) STAGE8(t + 2, (t + 2) % 3);  // into free buffer (2-ahead)
    const short* As = lds[b];
    const short* Bs = lds[b] + 256 * 64;
    bf16x8 af[4][2], bfr[4][2];
#pragma unroll
    for (int m = 0; m < 4; m++) {
      int row = wr + m * 16 + l16;
#pragma unroll
      for (int ks = 0; ks < 2; ks++)
        af[m][ks] = *(const bf16x8*)((const char*)As + row * 128 + (((ks * 4 + lg) ^ (row & 7)) * 16));
    }
#pragma unroll
    for (int n = 0; n < 4; n++) {
      int row = wc + n * 16 + l16;
#pragma unroll
      for (int ks = 0; ks < 2; ks++)
        bfr[n][ks] = *(const bf16x8*)((const char*)Bs + row * 128 + (((ks * 4 + lg) ^ (row & 7)) * 16));
    }
    __builtin_amdgcn_s_setprio(1);
#pragma unroll
    for (int ks = 0; ks < 2; ks++)
#pragma unroll
      for (int m = 0; m < 4; m++)
#pragma unroll
        for (int n = 0; n < 4; n++)
          acc[m][n] = __builtin_amdgcn_mfma_f32_16x16x32_bf16(af[m][ks], bfr[n][ks], acc[m][n], 0, 0, 0);
    __builtin_amdgcn_s_setprio(0);
    // tile boundary: require tile t+1 resident; keep tile t+2's 6 loads in flight
    if (t + 2 < NT) {
      asm volatile("s_waitcnt vmcnt(6)" ::: "memory");
    } else if (t + 1 < NT) {
      asm volatile("s_waitcnt vmcnt(0)" ::: "memory");
    }
    if (t + 1 < NT) {
      __builtin_amdgcn_s_barrier();
      __builtin_amdgcn_sched_barrier(0);
    }
  }
#undef STAGE8

  const int lr4 = lg * 4;
  if (KS == 1) {
#pragma unroll
    for (int m = 0; m < 4; m++)
#pragma unroll
      for (int n = 0; n < 4; n++)
#pragma unroll
        for (int r = 0; r < 4; r++) {
          long row = m0 + wr + m * 16 + lr4 + r;
          long col = n0 + wc + n * 16 + l16;
          if (col < N) {
            float v = acc[m][n][r];
            if (BIAS) v += bias[col];
            if (GELU) v = 0.5f * v * (1.f + erff(v * 0.70710678118f));
            if (RES) v += res[row * (long)N + col];
            if (OUTBF16) ((short*)Cout)[row * (long)N + col] = f2bf(v);
            else ((float*)Cout)[row * (long)N + col] = v;
          }
        }
  } else {
    long M = (long)gridDim.x * 256;
    float* P = (float*)Cout + (long)blockIdx.z * M * N;
#pragma unroll
    for (int m = 0; m < 4; m++)
#pragma unroll
      for (int n = 0; n < 4; n++)
#pragma unroll
        for (int r = 0; r < 4; r++) {
          long row = m0 + wr + m * 16 + lr4 + r;
          long col = n0 + wc + n * 16 + l16;
          P[row * (long)N + col] = acc[m][n][r];
        }
  }
}

// ---------------- split-K reduce: h += bias + sum partials ----------------
template <int KS>
__global__ void reduce_k(const float* __restrict__ part, const float* __restrict__ bias,
                         float* __restrict__ h, int N, long MN) {
  long i = ((long)blockIdx.x * 256 + threadIdx.x) * 4;
  if (i >= MN) return;
  fl4 s = *(const fl4*)(h + i);
  fl4 b = *(const fl4*)(bias + (int)(i % N));
  s[0] += b[0]; s[1] += b[1]; s[2] += b[2]; s[3] += b[3];
#pragma unroll
  for (int ks = 0; ks < KS; ks++) {
    fl4 p = *(const fl4*)(part + (long)ks * MN + i);
    s[0] += p[0]; s[1] += p[1]; s[2] += p[2]; s[3] += p[3];
  }
  *(fl4*)(h + i) = s;
}

// ---------------- MFMA flash attention, KVBLK=128 (R4, unchanged) ----------------
__global__ __launch_bounds__(256) void attn_mfma(const short* __restrict__ qkv,
                                                 const short* __restrict__ vtg,
                                                 short* __restrict__ Oa) {
  int hh = blockIdx.x, qb = blockIdx.y;
  int q0 = qb * 64;
  int tid = threadIdx.x, wv = tid >> 6, lane = tid & 63;
  int l16 = lane & 15, lg = lane >> 4;
  int hcol = hh * 64;
  __shared__ short Ks[KVB * 64];
  __shared__ short Vt[64 * KVB];
  __shared__ short Pl[4][16 * KVB];

  bf16x8 qf[2];
  {
    const short* qrow = qkv + (long)(q0 + wv * 16 + l16) * QKVD + hcol;
#pragma unroll
    for (int dc = 0; dc < 2; dc++) {
      bf16x8 t = *(const bf16x8*)(qrow + dc * 32 + lg * 8);
#pragma unroll
      for (int j = 0; j < 8; j++) t[j] = f2bf(bf2f(t[j]) * 0.125f);
      qf[dc] = t;
    }
  }
  f32x4 of[4] = {};
  float mrun[4], lrun[4];
#pragma unroll
  for (int r = 0; r < 4; r++) { mrun[r] = -3e38f; lrun[r] = 0.f; }

  int nt = qb / 2 + 1;
  for (int kt = 0; kt < nt; kt++) {
    int k0 = kt * KVB;
    __syncthreads();
#pragma unroll
    for (int i = 0; i < 4; i++) {
      int ca = i * 256 + tid;
      int row = ca >> 3, cp = ca & 7, c = cp ^ (row & 7);
      int ldsoff = (i * 256 + wv * 64) * 8;
      gload_lds16(qkv + (long)(k0 + row) * QKVD + DIM + hcol + c * 8, (short*)Ks + ldsoff);
    }
#pragma unroll
    for (int i = 0; i < 4; i++) {
      int ca = i * 256 + tid;
      int row = ca >> 4, cp = ca & 15, c = cp ^ (row & 7);
      int ldsoff = (i * 256 + wv * 64) * 8;
      gload_lds16(vtg + (long)(hcol + row) * SEQ + k0 + c * 8, (short*)Vt + ldsoff);
    }
    __syncthreads();

    f32x4 sacc[8] = {};
#pragma unroll
    for (int kc = 0; kc < 8; kc++) {
      int row = kc * 16 + l16;
#pragma unroll
      for (int dc = 0; dc < 2; dc++) {
        bf16x8 kf = *(const bf16x8*)((const char*)Ks + row * 128 + (((dc * 4 + lg) ^ (row & 7)) * 16));
        sacc[kc] = __builtin_amdgcn_mfma_f32_16x16x32_bf16(qf[dc], kf, sacc[kc], 0, 0, 0);
      }
    }

    float sv[8][4], pf[8][4];
#pragma unroll
    for (int kc = 0; kc < 8; kc++)
#pragma unroll
      for (int r = 0; r < 4; r++) sv[kc][r] = sacc[kc][r];
    if (kt == nt - 1) {
#pragma unroll
      for (int kc = 0; kc < 8; kc++)
#pragma unroll
        for (int r = 0; r < 4; r++) {
          int kg = k0 + kc * 16 + l16;
          int rg = q0 + wv * 16 + lg * 4 + r;
          if (kg > rg) sv[kc][r] = -3e38f;
        }
    }
    float corr[4];
#pragma unroll
    for (int r = 0; r < 4; r++) {
      float m01 = fmaxf(sv[0][r], sv[1][r]), m23 = fmaxf(sv[2][r], sv[3][r]);
      float m45 = fmaxf(sv[4][r], sv[5][r]), m67 = fmaxf(sv[6][r], sv[7][r]);
      float mt = fmaxf(fmaxf(m01, m23), fmaxf(m45, m67));
#pragma unroll
      for (int o = 8; o >= 1; o >>= 1) mt = fmaxf(mt, __shfl_xor(mt, o));
      float mn = fmaxf(mrun[r], mt);
      corr[r] = __expf(mrun[r] - mn);
      mrun[r] = mn;
      float ps = 0.f;
#pragma unroll
      for (int kc = 0; kc < 8; kc++) {
        float p = __expf(sv[kc][r] - mn);
        pf[kc][r] = p;
        ps += p;
      }
#pragma unroll
      for (int o = 8; o >= 1; o >>= 1) ps += __shfl_xor(ps, o);
      lrun[r] = lrun[r] * corr[r] + ps;
    }
#pragma unroll
    for (int c = 0; c < 4; c++)
#pragma unroll
      for (int r = 0; r < 4; r++) of[c][r] *= corr[r];
#pragma unroll
    for (int kc = 0; kc < 8; kc++)
#pragma unroll
      for (int r = 0; r < 4; r++) {
        int row = lg * 4 + r, col = kc * 16 + l16;
        int chunk = col >> 3;
        *(short*)((char*)Pl[wv] + row * 256 + ((chunk ^ (row & 7)) * 16) + (col & 7) * 2) = f2bf(pf[kc][r]);
      }
    bf16x8 pfr[4];
#pragma unroll
    for (int kc2 = 0; kc2 < 4; kc2++) {
      int cl = kc2 * 4 + lg;
      pfr[kc2] = *(const bf16x8*)((const char*)Pl[wv] + l16 * 256 + ((cl ^ (l16 & 7)) * 16));
    }
#pragma unroll
    for (int c = 0; c < 4; c++)
#pragma unroll
      for (int kc2 = 0; kc2 < 4; kc2++) {
        int vrow = c * 16 + l16;
        int cl = kc2 * 4 + lg;
        bf16x8 vf = *(const bf16x8*)((const char*)Vt + vrow * 256 + ((cl ^ (vrow & 7)) * 16));
        of[c] = __builtin_amdgcn_mfma_f32_16x16x32_bf16(pfr[kc2], vf, of[c], 0, 0, 0);
      }
  }
#pragma unroll
  for (int c = 0; c < 4; c++)
#pragma unroll
    for (int r = 0; r < 4; r++) {
      int rowg = q0 + wv * 16 + lg * 4 + r;
      int colg = hcol + c * 16 + l16;
      Oa[(long)rowg * DIM + colg] = f2bf(of[c][r] / lrun[r]);
    }
}

// ---------------- orchestration ----------------
extern "C" void kernel_launch(void* const* d_in, const int* in_sizes, int n_in,
                              void* d_out, int out_size, void* d_ws, size_t ws_size,
                              hipStream_t stream) {
  const int* ids = (const int*)d_in[0];
  const float* tok = (const float*)d_in[1];
  const float* pos = (const float*)d_in[2];
  const float* Wq = (const float*)d_in[3];
  const float* bq = (const float*)d_in[4];
  const float* Wk = (const float*)d_in[5];
  const float* bk = (const float*)d_in[6];
  const float* Wv = (const float*)d_in[7];
  const float* bv = (const float*)d_in[8];
  const float* Wo = (const float*)d_in[9];
  const float* bo = (const float*)d_in[10];
  const float* W1 = (const float*)d_in[11];
  const float* b1 = (const float*)d_in[12];
  const float* W2 = (const float*)d_in[13];
  const float* b2 = (const float*)d_in[14];
  const float* ln1w = (const float*)d_in[15];
  const float* ln1b = (const float*)d_in[16];
  const float* ln2w = (const float*)d_in[17];
  const float* ln2b = (const float*)d_in[18];
  const float* lnfw = (const float*)d_in[19];
  const float* lnfb = (const float*)d_in[20];
  const float* lmh = (const float*)d_in[21];
  float* out = (float*)d_out;

  char* wsb = (char*)d_ws;
  float* h = (float*)wsb;                           // 8 MB fp32 residual
  short* x = (short*)(wsb + 8388608);               // 4 MB bf16 LN out
  char* big = wsb + 8388608 + 4194304;
  short* qkv  = (short*)big;                        // 12 MB   [S][3072]
  short* a    = (short*)(big + 12582912);           // 4 MB    [S][1024]
  short* vt   = (short*)(big + 16777216);           // 4 MB    [1024][S]
  short* fbuf = (short*)(big + 20971520);           // 16 MB   [S][4096]
  float* pproj = (float*)fbuf;                      // proj partials: 2x8MB (fbuf free then)
  float* pffn2 = (float*)big;                       // ffn2 partials: 2x8MB (qkv+a free then)
  char* wdyn = big + 37748736;
  short* wqkvT = (short*)wdyn;                      // 6 MB  [3072][1024]
  short* woT   = (short*)(wdyn + 6291456);          // 2 MB  [1024][1024]
  short* w1T   = (short*)(wdyn + 8388608);          // 8 MB  [4096][1024]
  short* w2T   = (short*)(wdyn + 16777216);         // 8 MB  [1024][4096]
  float* bias3 = (float*)(wdyn + 25165824);         // 12 KB
  short* lmhB = (short*)big;                        // 103 MB, reused after layers

  const long MN = (long)SEQ * DIM;

  embed_kernel<<<(SEQ * DIM + 255) / 256, 256, 0, stream>>>(ids, tok, pos, h);

  dim3 gQKV(SEQ / 256, QKVD / 128);                 // 8 x 24
  dim3 gPROJ(SEQ / 256, DIM / 128, 2);              // 8 x 8 x 2 (split-K)
  dim3 gFFN1(SEQ / 256, FFN / 128);                 // 8 x 32
  dim3 gFFN2(SEQ / 256, DIM / 128, 2);              // 8 x 8 x 2 (split-K)
  dim3 gV(SEQ / 256, (VOCAB + 127) / 128);          // 8 x 393 = 3144

  for (int l = 0; l < NLAYER; l++) {
    TW4 tw;
    tw.src[0] = Wq + (long)l * DIM * DIM; tw.dst[0] = wqkvT;
    tw.src[1] = Wk + (long)l * DIM * DIM; tw.dst[1] = wqkvT + (long)DIM * DIM;
    tw.src[2] = Wv + (long)l * DIM * DIM; tw.dst[2] = wqkvT + (long)2 * DIM * DIM;
    tw.src[3] = Wo + (long)l * DIM * DIM; tw.dst[3] = woT;
    transpose_w4<<<dim3(32, 32, 4), 256, 0, stream>>>(tw);
    transpose_w<<<dim3(128, 32), 256, 0, stream>>>(W1 + (long)l * DIM * FFN, w1T, DIM, FFN);
    transpose_w<<<dim3(32, 128), 256, 0, stream>>>(W2 + (long)l * FFN * DIM, w2T, FFN, DIM);
    bias_cat<<<12, 256, 0, stream>>>(bq + (long)l * DIM, bk + (long)l * DIM, bv + (long)l * DIM, bias3);

    ln_kernel<<<SEQ, 256, 0, stream>>>(h, ln1w + (long)l * DIM, ln1b + (long)l * DIM, x);
    gemm8<false, false, true, true, 1, true><<<gQKV, 512, 0, stream>>>(x, wqkvT, bias3, nullptr, qkv, QKVD, DIM);
    transpose_v<<<dim3(SEQ / 64, DIM / 64), 256, 0, stream>>>(qkv, vt);
    attn_mfma<<<dim3(NHEAD, SEQ / 64), 256, 0, stream>>>(qkv, vt, a);
    gemm8<false, false, false, false, 2, true><<<gPROJ, 512, 0, stream>>>(a, woT, nullptr, nullptr, pproj, DIM, DIM);
    reduce_k<2><<<(int)(MN / 1024), 256, 0, stream>>>(pproj, bo + (long)l * DIM, h, DIM, MN);
    ln_kernel<<<SEQ, 256, 0, stream>>>(h, ln2w + (long)l * DIM, ln2b + (long)l * DIM, x);
    gemm8<true, false, true, true, 1, true><<<gFFN1, 512, 0, stream>>>(x, w1T, b1 + (long)l * FFN, nullptr, fbuf, FFN, DIM);
    gemm8<false, false, false, false, 2, true><<<gFFN2, 512, 0, stream>>>(fbuf, w2T, nullptr, nullptr, pffn2, DIM, FFN);
    reduce_k<2><<<(int)(MN / 1024), 256, 0, stream>>>(pffn2, b2 + (long)l * DIM, h, DIM, MN);
  }

  ln_kernel<<<SEQ, 256, 0, stream>>>(h, lnfw, lnfb, x);
  conv_bf16<<<2048, 256, 0, stream>>>(lmh, lmhB, (long)VOCAB * DIM / 4);
  gemm8<false, false, false, false, 1, true><<<gV, 512, 0, stream>>>(x, lmhB, nullptr, nullptr, out, VOCAB, DIM);
}